// Round 1
// baseline (492.528 us; speedup 1.0000x reference)
//
#include <hip/hip_runtime.h>
#include <math.h>

#define HW 4096      // 64*64 feature locations
#define CC 256       // feature channels
#define C2 64        // value channels
#define ALPHAc 100.0f
#define SHIFTc 50.0f
#define E50f 1.928749848e-22f   // expf(-50)

__device__ __forceinline__ float block_reduce_sum_256(float v, float* sbuf) {
    int t = threadIdx.x;
    sbuf[t] = v;
    __syncthreads();
    for (int s = 128; s > 0; s >>= 1) {
        if (t < s) sbuf[t] += sbuf[t + s];
        __syncthreads();
    }
    float r = sbuf[0];
    __syncthreads();
    return r;
}

// mu[0..255]=mean(fa[c]), mu[256..511]=mean(fb[c])
__global__ void k_channel_mean(const float* __restrict__ fa, const float* __restrict__ fb,
                               float* __restrict__ mu) {
    __shared__ float sbuf[256];
    int b = blockIdx.x;
    const float* src = (b < CC) ? (fa + b * HW) : (fb + (b - CC) * HW);
    float s = 0.f;
    for (int q = threadIdx.x; q < HW; q += 256) s += src[q];
    float tot = block_reduce_sum_256(s, sbuf);
    if (threadIdx.x == 0) mu[b] = tot * (1.0f / HW);
}

// center per channel, L2-normalize per location over channels
__global__ void k_normalize(const float* __restrict__ fa, const float* __restrict__ fb,
                            const float* __restrict__ mu,
                            float* __restrict__ fan, float* __restrict__ fbn) {
    __shared__ float smu[CC];
    int which = blockIdx.y;
    const float* src = which ? fb : fa;
    float* dst = which ? fbn : fan;
    int t = threadIdx.x;
    smu[t] = mu[which * CC + t];
    __syncthreads();
    int p = blockIdx.x * 256 + t;
    float ss = 0.f;
    for (int c = 0; c < CC; ++c) {
        float v = src[c * HW + p] - smu[c];
        ss += v * v;
    }
    float inv = 1.0f / sqrtf(ss);
    for (int c = 0; c < CC; ++c) {
        float v = src[c * HW + p] - smu[c];
        dst[c * HW + p] = v * inv;
    }
}

// nearest-downsampled parse masks (channels 1..3), norm_a = max(sum_k mask_a, 1)
__global__ void k_masks(const int* __restrict__ fa_parse, const int* __restrict__ fb_parse,
                        float* __restrict__ mask_a, float* __restrict__ mask_b,
                        float* __restrict__ norm_a) {
    int p = blockIdx.x * 256 + threadIdx.x;
    int j = p >> 6, i = p & 63;
    int off = (4 * j) * 256 + 4 * i;   // nearest: src = 4*dst
    float s = 0.f;
    for (int k = 0; k < 3; ++k) {
        float a = (fa_parse[(k + 1) * 65536 + off] != 0) ? 1.f : 0.f;
        float b = (fb_parse[(k + 1) * 65536 + off] != 0) ? 1.f : 0.f;
        mask_a[k * HW + p] = a;
        mask_b[k * HW + p] = b;
        s += a;
    }
    norm_a[p] = fmaxf(s, 1.f);
}

// bilinear align_corners 256->64 of unalign_fb -> ufb[c2][hw]
__global__ void k_bilin_down(const float* __restrict__ src, float* __restrict__ ufb) {
    int p = blockIdx.x * 256 + threadIdx.x;
    int c = blockIdx.y;
    int j = p >> 6, i = p & 63;
    float ry = j * (255.0f / 63.0f);
    int y0 = (int)ry; y0 = min(y0, 255); int y1 = min(y0 + 1, 255);
    float wy = ry - (float)y0;
    float rx = i * (255.0f / 63.0f);
    int x0 = (int)rx; x0 = min(x0, 255); int x1 = min(x0 + 1, 255);
    float wx = rx - (float)x0;
    const float* sc = src + c * 65536;
    float r0 = sc[y0 * 256 + x0] * (1.f - wx) + sc[y0 * 256 + x1] * wx;
    float r1 = sc[y1 * 256 + x0] * (1.f - wx) + sc[y1 * 256 + x1] * wx;
    ufb[c * HW + p] = r0 * (1.f - wy) + r1 * wy;
}

// vt[q][m], m = k*65 + c2 : masked values (c2<64 -> mask_b*ufb, c2==64 -> mask_b*1), rows 195..255 zero
__global__ void k_build_vt(const float* __restrict__ ufb, const float* __restrict__ mask_b,
                           float* __restrict__ vt) {
    int q = blockIdx.x;
    int m = threadIdx.x;
    float v = 0.f;
    if (m < 195) {
        int k = m / 65, c2 = m % 65;
        float base = (c2 < 64) ? ufb[c2 * HW + q] : 1.0f;
        v = base * mask_b[k * HW + q];
    }
    vt[q * 256 + m] = v;
}

// bg[r] = sum_q (1-mask_b[k][q]) * (c2<64 ? ufb[c2][q] : 1)
__global__ void k_bg(const float* __restrict__ ufb, const float* __restrict__ mask_b,
                     float* __restrict__ bg) {
    __shared__ float sbuf[256];
    int r = blockIdx.x;
    int k = r / 65, c2 = r % 65;
    float s = 0.f;
    for (int q = threadIdx.x; q < HW; q += 256) {
        float base = (c2 < 64) ? ufb[c2 * HW + q] : 1.0f;
        s += base * (1.0f - mask_b[k * HW + q]);
    }
    float tot = block_reduce_sum_256(s, sbuf);
    if (threadIdx.x == 0) bg[r] = tot;
}

// S[qloc][p] = sum_c fbn[c][q0+qloc] * fan[c][p], 64x64 tiles, 4x4 micro
__global__ __launch_bounds__(256) void k_gemm_s(const float* __restrict__ fbn,
                                                const float* __restrict__ fan,
                                                float* __restrict__ S, int q0) {
    __shared__ float Al[16][64];
    __shared__ float Bl[16][64];
    int t = threadIdx.x;
    int pbase = blockIdx.x * 64;
    int qbase = blockIdx.y * 64;
    int lr = t >> 4, lc = (t & 15) << 2;
    int qq = (t & 15) << 2, pp = (t >> 4) << 2;
    float acc[4][4] = {};
    for (int c0 = 0; c0 < CC; c0 += 16) {
        __syncthreads();
        *(float4*)&Al[lr][lc] = *(const float4*)&fbn[(c0 + lr) * HW + q0 + qbase + lc];
        *(float4*)&Bl[lr][lc] = *(const float4*)&fan[(c0 + lr) * HW + pbase + lc];
        __syncthreads();
#pragma unroll
        for (int c = 0; c < 16; ++c) {
            float4 a = *(float4*)&Al[c][qq];
            float4 b = *(float4*)&Bl[c][pp];
            acc[0][0] += a.x * b.x; acc[0][1] += a.x * b.y; acc[0][2] += a.x * b.z; acc[0][3] += a.x * b.w;
            acc[1][0] += a.y * b.x; acc[1][1] += a.y * b.y; acc[1][2] += a.y * b.z; acc[1][3] += a.y * b.w;
            acc[2][0] += a.z * b.x; acc[2][1] += a.z * b.y; acc[2][2] += a.z * b.z; acc[2][3] += a.z * b.w;
            acc[3][0] += a.w * b.x; acc[3][1] += a.w * b.y; acc[3][2] += a.w * b.z; acc[3][3] += a.w * b.w;
        }
    }
#pragma unroll
    for (int iq = 0; iq < 4; ++iq) {
        float4 o;
        o.x = acc[iq][0]; o.y = acc[iq][1]; o.z = acc[iq][2]; o.w = acc[iq][3];
        *(float4*)&S[(qbase + qq + iq) * HW + pbase + pp] = o;
    }
}

// acc[m][p] += sum_{qloc} vt[q0+qloc][m] * exp(100*S[qloc][p] - 50)
__global__ __launch_bounds__(256) void k_pv(const float* __restrict__ vt,
                                            const float* __restrict__ S,
                                            float* __restrict__ acc_g, int q0) {
    __shared__ float Vl[16][64];
    __shared__ float El[16][64];
    int t = threadIdx.x;
    int pbase = blockIdx.x * 64;
    int mbase = blockIdx.y * 64;
    int lr = t >> 4, lc = (t & 15) << 2;
    int mm = (t & 15) << 2, pp = (t >> 4) << 2;
    float acc[4][4] = {};
    for (int k0 = 0; k0 < 1024; k0 += 16) {
        __syncthreads();
        *(float4*)&Vl[lr][lc] = *(const float4*)&vt[(q0 + k0 + lr) * 256 + mbase + lc];
        float4 s4 = *(const float4*)&S[(k0 + lr) * HW + pbase + lc];
        float4 e4;
        e4.x = __expf(ALPHAc * s4.x - SHIFTc);
        e4.y = __expf(ALPHAc * s4.y - SHIFTc);
        e4.z = __expf(ALPHAc * s4.z - SHIFTc);
        e4.w = __expf(ALPHAc * s4.w - SHIFTc);
        *(float4*)&El[lr][lc] = e4;
        __syncthreads();
#pragma unroll
        for (int q = 0; q < 16; ++q) {
            float4 v = *(float4*)&Vl[q][mm];
            float4 e = *(float4*)&El[q][pp];
            acc[0][0] += v.x * e.x; acc[0][1] += v.x * e.y; acc[0][2] += v.x * e.z; acc[0][3] += v.x * e.w;
            acc[1][0] += v.y * e.x; acc[1][1] += v.y * e.y; acc[1][2] += v.y * e.z; acc[1][3] += v.y * e.w;
            acc[2][0] += v.z * e.x; acc[2][1] += v.z * e.y; acc[2][2] += v.z * e.z; acc[2][3] += v.z * e.w;
            acc[3][0] += v.w * e.x; acc[3][1] += v.w * e.y; acc[3][2] += v.w * e.z; acc[3][3] += v.w * e.w;
        }
    }
#pragma unroll
    for (int im = 0; im < 4; ++im) {
        float* dst = &acc_g[(mbase + mm + im) * HW + pbase + pp];
        float4 o = *(float4*)dst;
        o.x += acc[im][0]; o.y += acc[im][1]; o.z += acc[im][2]; o.w += acc[im][3];
        *(float4*)dst = o;
    }
}

// aligned[c2][p] = sum_k mask_a * (acc_num + e50*bg_num)/(acc_den + e50*bg_den) / norm_a
__global__ void k_combine(const float* __restrict__ acc_g, const float* __restrict__ bg,
                          const float* __restrict__ mask_a, const float* __restrict__ norm_a,
                          float* __restrict__ aligned) {
    int p = blockIdx.x * 256 + threadIdx.x;
    int c2 = blockIdx.y;
    float num = 0.f;
    for (int k = 0; k < 3; ++k) {
        float ma = mask_a[k * HW + p];
        float l  = acc_g[(k * 65 + 64) * HW + p] + E50f * bg[k * 65 + 64];
        float nu = acc_g[(k * 65 + c2) * HW + p] + E50f * bg[k * 65 + c2];
        num += ma * (nu / l);
    }
    aligned[c2 * HW + p] = num / norm_a[p];
}

// bilinear align_corners 64->256
__global__ void k_bilin_up(const float* __restrict__ aligned, float* __restrict__ out) {
    int idx = blockIdx.x * 256 + threadIdx.x;   // 0..65535
    int c2 = blockIdx.y;
    int y = idx >> 8, x = idx & 255;
    float ry = y * (63.0f / 255.0f);
    int y0 = (int)ry; y0 = min(y0, 63); int y1 = min(y0 + 1, 63);
    float wy = ry - (float)y0;
    float rx = x * (63.0f / 255.0f);
    int x0 = (int)rx; x0 = min(x0, 63); int x1 = min(x0 + 1, 63);
    float wx = rx - (float)x0;
    const float* a = aligned + c2 * HW;
    float r0 = a[y0 * 64 + x0] * (1.f - wx) + a[y0 * 64 + x1] * wx;
    float r1 = a[y1 * 64 + x0] * (1.f - wx) + a[y1 * 64 + x1] * wx;
    out[c2 * 65536 + idx] = r0 * (1.f - wy) + r1 * wy;
}

extern "C" void kernel_launch(void* const* d_in, const int* in_sizes, int n_in,
                              void* d_out, int out_size, void* d_ws, size_t ws_size,
                              hipStream_t stream) {
    const float* unalign_fb = (const float*)d_in[0];   // (1,64,256,256)
    const float* fa         = (const float*)d_in[1];   // (1,256,64,64)
    const int*   fa_parse   = (const int*)d_in[2];     // (1,4,256,256)
    const float* fb         = (const float*)d_in[3];   // (1,256,64,64)
    const int*   fb_parse   = (const int*)d_in[4];     // (1,4,256,256)
    float* out = (float*)d_out;                         // (1,64,256,256)

    float* w = (float*)d_ws;
    float* mu      = w;                 // 512
    float* mask_a  = w + 512;           // 3*4096
    float* mask_b  = w + 12800;         // 3*4096
    float* norm_a  = w + 25088;         // 4096
    float* bg      = w + 29184;         // 256 (195 used)
    float* fan     = w + 29440;         // 256*4096
    float* fbn     = fan + CC * HW;     // 256*4096
    float* ufb     = fbn + CC * HW;     // 64*4096
    float* vt      = ufb + C2 * HW;     // 4096*256
    float* accb    = vt + HW * 256;     // 256*4096
    float* aligned = accb + 256 * HW;   // 64*4096
    float* Sbuf    = aligned + C2 * HW; // 1024*4096
    // total ~8.94M floats = ~35.8 MB

    k_channel_mean<<<dim3(512), dim3(256), 0, stream>>>(fa, fb, mu);
    k_normalize<<<dim3(16, 2), dim3(256), 0, stream>>>(fa, fb, mu, fan, fbn);
    k_masks<<<dim3(16), dim3(256), 0, stream>>>(fa_parse, fb_parse, mask_a, mask_b, norm_a);
    k_bilin_down<<<dim3(16, 64), dim3(256), 0, stream>>>(unalign_fb, ufb);
    k_build_vt<<<dim3(4096), dim3(256), 0, stream>>>(ufb, mask_b, vt);
    k_bg<<<dim3(195), dim3(256), 0, stream>>>(ufb, mask_b, bg);
    hipMemsetAsync(accb, 0, 256 * HW * sizeof(float), stream);

    for (int ci = 0; ci < 4; ++ci) {
        int q0 = ci * 1024;
        k_gemm_s<<<dim3(64, 16), dim3(256), 0, stream>>>(fbn, fan, Sbuf, q0);
        k_pv<<<dim3(64, 4), dim3(256), 0, stream>>>(vt, Sbuf, accb, q0);
    }

    k_combine<<<dim3(16, 64), dim3(256), 0, stream>>>(accb, bg, mask_a, norm_a, aligned);
    k_bilin_up<<<dim3(256, 64), dim3(256), 0, stream>>>(aligned, out);
}

// Round 2
// 372.896 us; speedup vs baseline: 1.3208x; 1.3208x over previous
//
#include <hip/hip_runtime.h>
#include <math.h>

#define HW 4096      // 64*64 feature locations
#define CC 256       // feature channels
#define C2 64        // value channels
#define ALPHAc 100.0f
#define SHIFTc 50.0f
#define E50f 1.928749848e-22f   // expf(-50)

__device__ __forceinline__ float block_reduce_sum_256(float v, float* sbuf) {
    int t = threadIdx.x;
    sbuf[t] = v;
    __syncthreads();
    for (int s = 128; s > 0; s >>= 1) {
        if (t < s) sbuf[t] += sbuf[t + s];
        __syncthreads();
    }
    float r = sbuf[0];
    __syncthreads();
    return r;
}

// mu[0..255]=mean(fa[c]), mu[256..511]=mean(fb[c])
__global__ void k_channel_mean(const float* __restrict__ fa, const float* __restrict__ fb,
                               float* __restrict__ mu) {
    __shared__ float sbuf[256];
    int b = blockIdx.x;
    const float* src = (b < CC) ? (fa + b * HW) : (fb + (b - CC) * HW);
    float s = 0.f;
    for (int q = threadIdx.x; q < HW; q += 256) s += src[q];
    float tot = block_reduce_sum_256(s, sbuf);
    if (threadIdx.x == 0) mu[b] = tot * (1.0f / HW);
}

// partial sum of squares over c-chunks -> ssq[which][p] via atomics
__global__ void k_norm_ss(const float* __restrict__ fa, const float* __restrict__ fb,
                          const float* __restrict__ mu, float* __restrict__ ssq) {
    int which = blockIdx.z;
    const float* src = which ? fb : fa;
    int p = blockIdx.x * 256 + threadIdx.x;
    int c0 = blockIdx.y * 32;
    float ss = 0.f;
    for (int c = c0; c < c0 + 32; ++c) {
        float v = src[c * HW + p] - mu[which * CC + c];
        ss += v * v;
    }
    atomicAdd(&ssq[which * HW + p], ss);
}

// apply centering + per-location L2 normalization, fully parallel
__global__ void k_norm_apply(const float* __restrict__ fa, const float* __restrict__ fb,
                             const float* __restrict__ mu, const float* __restrict__ ssq,
                             float* __restrict__ fan, float* __restrict__ fbn) {
    int which = blockIdx.y;
    const float* src = which ? fb : fa;
    float* dst = which ? fbn : fan;
    int idx = (blockIdx.x * 256 + threadIdx.x) * 4;
    int c = idx >> 12;          // / 4096
    int p = idx & 4095;
    float m = mu[which * CC + c];
    float4 v = *(const float4*)&src[idx];
    float4 s4 = *(const float4*)&ssq[which * HW + p];
    v.x = (v.x - m) * rsqrtf(s4.x);
    v.y = (v.y - m) * rsqrtf(s4.y);
    v.z = (v.z - m) * rsqrtf(s4.z);
    v.w = (v.w - m) * rsqrtf(s4.w);
    *(float4*)&dst[idx] = v;
}

// nearest-downsampled parse masks (channels 1..3), norm_a = max(sum_k mask_a, 1)
__global__ void k_masks(const int* __restrict__ fa_parse, const int* __restrict__ fb_parse,
                        float* __restrict__ mask_a, float* __restrict__ mask_b,
                        float* __restrict__ norm_a) {
    int p = blockIdx.x * 256 + threadIdx.x;
    int j = p >> 6, i = p & 63;
    int off = (4 * j) * 256 + 4 * i;   // nearest: src = 4*dst
    float s = 0.f;
    for (int k = 0; k < 3; ++k) {
        float a = (fa_parse[(k + 1) * 65536 + off] != 0) ? 1.f : 0.f;
        float b = (fb_parse[(k + 1) * 65536 + off] != 0) ? 1.f : 0.f;
        mask_a[k * HW + p] = a;
        mask_b[k * HW + p] = b;
        s += a;
    }
    norm_a[p] = fmaxf(s, 1.f);
}

// bilinear align_corners 256->64 of unalign_fb -> ufb[c2][hw]
__global__ void k_bilin_down(const float* __restrict__ src, float* __restrict__ ufb) {
    int p = blockIdx.x * 256 + threadIdx.x;
    int c = blockIdx.y;
    int j = p >> 6, i = p & 63;
    float ry = j * (255.0f / 63.0f);
    int y0 = (int)ry; y0 = min(y0, 255); int y1 = min(y0 + 1, 255);
    float wy = ry - (float)y0;
    float rx = i * (255.0f / 63.0f);
    int x0 = (int)rx; x0 = min(x0, 255); int x1 = min(x0 + 1, 255);
    float wx = rx - (float)x0;
    const float* sc = src + c * 65536;
    float r0 = sc[y0 * 256 + x0] * (1.f - wx) + sc[y0 * 256 + x1] * wx;
    float r1 = sc[y1 * 256 + x0] * (1.f - wx) + sc[y1 * 256 + x1] * wx;
    ufb[c * HW + p] = r0 * (1.f - wy) + r1 * wy;
}

// vt[q][m], m = k*65 + c2 : masked values (c2<64 -> mask_b*ufb, c2==64 -> mask_b*1)
__global__ void k_build_vt(const float* __restrict__ ufb, const float* __restrict__ mask_b,
                           float* __restrict__ vt) {
    int q = blockIdx.x;
    int m = threadIdx.x;
    float v = 0.f;
    if (m < 195) {
        int k = m / 65, c2 = m % 65;
        float base = (c2 < 64) ? ufb[c2 * HW + q] : 1.0f;
        v = base * mask_b[k * HW + q];
    }
    vt[q * 256 + m] = v;
}

// bg[r] = sum_q (1-mask_b[k][q]) * (c2<64 ? ufb[c2][q] : 1)
__global__ void k_bg(const float* __restrict__ ufb, const float* __restrict__ mask_b,
                     float* __restrict__ bg) {
    __shared__ float sbuf[256];
    int r = blockIdx.x;
    int k = r / 65, c2 = r % 65;
    float s = 0.f;
    for (int q = threadIdx.x; q < HW; q += 256) {
        float base = (c2 < 64) ? ufb[c2 * HW + q] : 1.0f;
        s += base * (1.0f - mask_b[k * HW + q]);
    }
    float tot = block_reduce_sum_256(s, sbuf);
    if (threadIdx.x == 0) bg[r] = tot;
}

// E[qloc][p] = exp(100 * sum_c fbn[c][q0+qloc]*fan[c][p] - 50)
// 64(q) x 128(p) tile, 4x8 micro, double-buffered LDS staging
__global__ __launch_bounds__(256) void k_gemm_s_exp(const float* __restrict__ fbn,
                                                    const float* __restrict__ fan,
                                                    float* __restrict__ E, int q0) {
    __shared__ float Al[2][16][64];
    __shared__ float Bl[2][16][128];
    int t = threadIdx.x;
    int pbase = blockIdx.x * 128;
    int qbase = blockIdx.y * 64;
    int sr = t >> 4;            // staging row 0..15
    int sca = (t & 15) * 4;     // A staging col
    int scb = (t & 15) * 8;     // B staging col
    int qq = (t & 15) * 4;      // micro m
    int pp = (t >> 4) * 8;      // micro n
    float acc[4][8] = {};

    float4 ra  = *(const float4*)&fbn[sr * HW + q0 + qbase + sca];
    float4 rb0 = *(const float4*)&fan[sr * HW + pbase + scb];
    float4 rb1 = *(const float4*)&fan[sr * HW + pbase + scb + 4];
    *(float4*)&Al[0][sr][sca] = ra;
    *(float4*)&Bl[0][sr][scb] = rb0;
    *(float4*)&Bl[0][sr][scb + 4] = rb1;
    __syncthreads();
    int cur = 0;
    for (int kt = 0; kt < 16; ++kt) {
        if (kt < 15) {
            int c0 = (kt + 1) * 16;
            ra  = *(const float4*)&fbn[(c0 + sr) * HW + q0 + qbase + sca];
            rb0 = *(const float4*)&fan[(c0 + sr) * HW + pbase + scb];
            rb1 = *(const float4*)&fan[(c0 + sr) * HW + pbase + scb + 4];
        }
#pragma unroll
        for (int k = 0; k < 16; ++k) {
            float4 a  = *(float4*)&Al[cur][k][qq];
            float4 b0 = *(float4*)&Bl[cur][k][pp];
            float4 b1 = *(float4*)&Bl[cur][k][pp + 4];
            float av[4] = {a.x, a.y, a.z, a.w};
            float bv[8] = {b0.x, b0.y, b0.z, b0.w, b1.x, b1.y, b1.z, b1.w};
#pragma unroll
            for (int i = 0; i < 4; ++i)
#pragma unroll
                for (int j = 0; j < 8; ++j) acc[i][j] += av[i] * bv[j];
        }
        if (kt < 15) {
            *(float4*)&Al[cur ^ 1][sr][sca] = ra;
            *(float4*)&Bl[cur ^ 1][sr][scb] = rb0;
            *(float4*)&Bl[cur ^ 1][sr][scb + 4] = rb1;
        }
        __syncthreads();
        cur ^= 1;
    }
#pragma unroll
    for (int i = 0; i < 4; ++i) {
        float4 o0, o1;
        o0.x = __expf(ALPHAc * acc[i][0] - SHIFTc);
        o0.y = __expf(ALPHAc * acc[i][1] - SHIFTc);
        o0.z = __expf(ALPHAc * acc[i][2] - SHIFTc);
        o0.w = __expf(ALPHAc * acc[i][3] - SHIFTc);
        o1.x = __expf(ALPHAc * acc[i][4] - SHIFTc);
        o1.y = __expf(ALPHAc * acc[i][5] - SHIFTc);
        o1.z = __expf(ALPHAc * acc[i][6] - SHIFTc);
        o1.w = __expf(ALPHAc * acc[i][7] - SHIFTc);
        *(float4*)&E[(qbase + qq + i) * HW + pbase + pp] = o0;
        *(float4*)&E[(qbase + qq + i) * HW + pbase + pp + 4] = o1;
    }
}

// part[z][m][p] += sum_{q in z-chunk} vt[q][m] * E[q][p]
// 64(m) x 128(p) tile, 4x8 micro, dbuf, K=256 per block (z-split)
__global__ __launch_bounds__(256) void k_pv(const float* __restrict__ vt,
                                            const float* __restrict__ E,
                                            float* __restrict__ part, int q0) {
    __shared__ float Al[2][16][64];
    __shared__ float Bl[2][16][128];
    int t = threadIdx.x;
    int pbase = blockIdx.x * 128;
    int mbase = blockIdx.y * 64;
    int z = blockIdx.z;
    const float* Ez = E + (size_t)z * 256 * HW;          // chunk rows z*256..
    const float* vz = vt + (size_t)(q0 + z * 256) * 256; // matching vt rows
    float* outp = part + (size_t)z * (256 * HW);
    int sr = t >> 4;
    int sca = (t & 15) * 4;
    int scb = (t & 15) * 8;
    int mm = (t & 15) * 4;
    int pp = (t >> 4) * 8;
    float acc[4][8] = {};

    float4 ra  = *(const float4*)&vz[sr * 256 + mbase + sca];
    float4 rb0 = *(const float4*)&Ez[sr * HW + pbase + scb];
    float4 rb1 = *(const float4*)&Ez[sr * HW + pbase + scb + 4];
    *(float4*)&Al[0][sr][sca] = ra;
    *(float4*)&Bl[0][sr][scb] = rb0;
    *(float4*)&Bl[0][sr][scb + 4] = rb1;
    __syncthreads();
    int cur = 0;
    for (int kt = 0; kt < 16; ++kt) {
        if (kt < 15) {
            int r0 = (kt + 1) * 16;
            ra  = *(const float4*)&vz[(r0 + sr) * 256 + mbase + sca];
            rb0 = *(const float4*)&Ez[(r0 + sr) * HW + pbase + scb];
            rb1 = *(const float4*)&Ez[(r0 + sr) * HW + pbase + scb + 4];
        }
#pragma unroll
        for (int k = 0; k < 16; ++k) {
            float4 a  = *(float4*)&Al[cur][k][mm];
            float4 b0 = *(float4*)&Bl[cur][k][pp];
            float4 b1 = *(float4*)&Bl[cur][k][pp + 4];
            float av[4] = {a.x, a.y, a.z, a.w};
            float bv[8] = {b0.x, b0.y, b0.z, b0.w, b1.x, b1.y, b1.z, b1.w};
#pragma unroll
            for (int i = 0; i < 4; ++i)
#pragma unroll
                for (int j = 0; j < 8; ++j) acc[i][j] += av[i] * bv[j];
        }
        if (kt < 15) {
            *(float4*)&Al[cur ^ 1][sr][sca] = ra;
            *(float4*)&Bl[cur ^ 1][sr][scb] = rb0;
            *(float4*)&Bl[cur ^ 1][sr][scb + 4] = rb1;
        }
        __syncthreads();
        cur ^= 1;
    }
#pragma unroll
    for (int i = 0; i < 4; ++i) {
        float* dst = &outp[(size_t)(mbase + mm + i) * HW + pbase + pp];
        float4 o0 = *(float4*)dst;
        float4 o1 = *(float4*)(dst + 4);
        o0.x += acc[i][0]; o0.y += acc[i][1]; o0.z += acc[i][2]; o0.w += acc[i][3];
        o1.x += acc[i][4]; o1.y += acc[i][5]; o1.z += acc[i][6]; o1.w += acc[i][7];
        *(float4*)dst = o0;
        *(float4*)(dst + 4) = o1;
    }
}

// part[0] += part[1] + part[2] + part[3]
__global__ void k_reduce(float* __restrict__ part) {
    int i = (blockIdx.x * 256 + threadIdx.x) * 4;
    float4 a = *(float4*)&part[i];
    float4 b = *(float4*)&part[1048576 + i];
    float4 c = *(float4*)&part[2097152 + i];
    float4 d = *(float4*)&part[3145728 + i];
    a.x += b.x + c.x + d.x;
    a.y += b.y + c.y + d.y;
    a.z += b.z + c.z + d.z;
    a.w += b.w + c.w + d.w;
    *(float4*)&part[i] = a;
}

// aligned[c2][p] = sum_k mask_a * (acc_num + e50*bg_num)/(acc_den + e50*bg_den) / norm_a
__global__ void k_combine(const float* __restrict__ acc_g, const float* __restrict__ bg,
                          const float* __restrict__ mask_a, const float* __restrict__ norm_a,
                          float* __restrict__ aligned) {
    int p = blockIdx.x * 256 + threadIdx.x;
    int c2 = blockIdx.y;
    float num = 0.f;
    for (int k = 0; k < 3; ++k) {
        float ma = mask_a[k * HW + p];
        float l  = acc_g[(k * 65 + 64) * HW + p] + E50f * bg[k * 65 + 64];
        float nu = acc_g[(k * 65 + c2) * HW + p] + E50f * bg[k * 65 + c2];
        num += ma * (nu / l);
    }
    aligned[c2 * HW + p] = num / norm_a[p];
}

// bilinear align_corners 64->256
__global__ void k_bilin_up(const float* __restrict__ aligned, float* __restrict__ out) {
    int idx = blockIdx.x * 256 + threadIdx.x;   // 0..65535
    int c2 = blockIdx.y;
    int y = idx >> 8, x = idx & 255;
    float ry = y * (63.0f / 255.0f);
    int y0 = (int)ry; y0 = min(y0, 63); int y1 = min(y0 + 1, 63);
    float wy = ry - (float)y0;
    float rx = x * (63.0f / 255.0f);
    int x0 = (int)rx; x0 = min(x0, 63); int x1 = min(x0 + 1, 63);
    float wx = rx - (float)x0;
    const float* a = aligned + c2 * HW;
    float r0 = a[y0 * 64 + x0] * (1.f - wx) + a[y0 * 64 + x1] * wx;
    float r1 = a[y1 * 64 + x0] * (1.f - wx) + a[y1 * 64 + x1] * wx;
    out[c2 * 65536 + idx] = r0 * (1.f - wy) + r1 * wy;
}

extern "C" void kernel_launch(void* const* d_in, const int* in_sizes, int n_in,
                              void* d_out, int out_size, void* d_ws, size_t ws_size,
                              hipStream_t stream) {
    const float* unalign_fb = (const float*)d_in[0];   // (1,64,256,256)
    const float* fa         = (const float*)d_in[1];   // (1,256,64,64)
    const int*   fa_parse   = (const int*)d_in[2];     // (1,4,256,256)
    const float* fb         = (const float*)d_in[3];   // (1,256,64,64)
    const int*   fb_parse   = (const int*)d_in[4];     // (1,4,256,256)
    float* out = (float*)d_out;                         // (1,64,256,256)

    float* w = (float*)d_ws;
    float* mu      = w;                  // 512
    float* mask_a  = w + 512;            // 12288
    float* mask_b  = w + 12800;          // 12288
    float* norm_a  = w + 25088;          // 4096
    float* bg      = w + 29184;          // 256
    float* ssq     = w + 29440;          // 8192
    float* fan     = w + 37632;          // 1048576
    float* fbn     = fan + CC * HW;      // 1048576
    float* ufb     = fbn + CC * HW;      // 262144
    float* vt      = ufb + C2 * HW;      // 1048576
    float* part    = vt + HW * 256;      // 4*1048576
    float* aligned = part + 4 * 1048576; // 262144
    float* Ebuf    = aligned + C2 * HW;  // 1024*4096 = 4194304
    // total ~12.1M floats = ~48.4 MB

    k_channel_mean<<<dim3(512), dim3(256), 0, stream>>>(fa, fb, mu);
    hipMemsetAsync(ssq, 0, 2 * HW * sizeof(float), stream);
    k_norm_ss<<<dim3(16, 8, 2), dim3(256), 0, stream>>>(fa, fb, mu, ssq);
    k_norm_apply<<<dim3(1024, 2), dim3(256), 0, stream>>>(fa, fb, mu, ssq, fan, fbn);
    k_masks<<<dim3(16), dim3(256), 0, stream>>>(fa_parse, fb_parse, mask_a, mask_b, norm_a);
    k_bilin_down<<<dim3(16, 64), dim3(256), 0, stream>>>(unalign_fb, ufb);
    k_build_vt<<<dim3(4096), dim3(256), 0, stream>>>(ufb, mask_b, vt);
    k_bg<<<dim3(195), dim3(256), 0, stream>>>(ufb, mask_b, bg);
    hipMemsetAsync(part, 0, 4 * 1048576 * sizeof(float), stream);

    for (int ci = 0; ci < 4; ++ci) {
        int q0 = ci * 1024;
        k_gemm_s_exp<<<dim3(32, 16), dim3(256), 0, stream>>>(fbn, fan, Ebuf, q0);
        k_pv<<<dim3(32, 4, 4), dim3(256), 0, stream>>>(vt, Ebuf, part, q0);
    }

    k_reduce<<<dim3(1024), dim3(256), 0, stream>>>(part);
    k_combine<<<dim3(16, 64), dim3(256), 0, stream>>>(part, bg, mask_a, norm_a, aligned);
    k_bilin_up<<<dim3(256, 64), dim3(256), 0, stream>>>(aligned, out);
}

// Round 3
// 197.575 us; speedup vs baseline: 2.4929x; 1.8874x over previous
//
#include <hip/hip_runtime.h>
#include <math.h>

#define HW 4096      // 64*64 feature locations
#define CC 256       // feature channels
#define C2 64        // value channels
#define E50f 1.928749848e-22f   // expf(-50)

typedef __attribute__((ext_vector_type(8))) short bf8;
typedef __attribute__((ext_vector_type(4))) float f32x4;

__device__ __forceinline__ unsigned short f2bf(float x) {
    unsigned u = __float_as_uint(x);
    u += 0x7fff + ((u >> 16) & 1);   // round-to-nearest-even
    return (unsigned short)(u >> 16);
}
__device__ __forceinline__ float bf2f(unsigned short h) {
    return __uint_as_float(((unsigned)h) << 16);
}

__device__ __forceinline__ float block_reduce_sum_256(float v, float* sbuf) {
    int t = threadIdx.x;
    sbuf[t] = v;
    __syncthreads();
    for (int s = 128; s > 0; s >>= 1) {
        if (t < s) sbuf[t] += sbuf[t + s];
        __syncthreads();
    }
    float r = sbuf[0];
    __syncthreads();
    return r;
}

// mu[0..255]=mean(fa[c]), mu[256..511]=mean(fb[c])
__global__ void k_channel_mean(const float* __restrict__ fa, const float* __restrict__ fb,
                               float* __restrict__ mu) {
    __shared__ float sbuf[256];
    int b = blockIdx.x;
    const float* src = (b < CC) ? (fa + b * HW) : (fb + (b - CC) * HW);
    float s = 0.f;
    for (int q = threadIdx.x; q < HW; q += 256) s += src[q];
    float tot = block_reduce_sum_256(s, sbuf);
    if (threadIdx.x == 0) mu[b] = tot * (1.0f / HW);
}

// partial sum of squares over c-chunks -> ssq[which][p] via atomics
__global__ void k_norm_ss(const float* __restrict__ fa, const float* __restrict__ fb,
                          const float* __restrict__ mu, float* __restrict__ ssq) {
    int which = blockIdx.z;
    const float* src = which ? fb : fa;
    int p = blockIdx.x * 256 + threadIdx.x;
    int c0 = blockIdx.y * 32;
    float ss = 0.f;
    for (int c = c0; c < c0 + 32; ++c) {
        float v = src[c * HW + p] - mu[which * CC + c];
        ss += v * v;
    }
    atomicAdd(&ssq[which * HW + p], ss);
}

// fused: center + L2-normalize + hi/lo bf16 split + transpose [c][p] -> [p][c]
__global__ __launch_bounds__(256) void k_norm_split_t(
    const float* __restrict__ fa, const float* __restrict__ fb,
    const float* __restrict__ mu, const float* __restrict__ ssq,
    unsigned short* __restrict__ faT_hi, unsigned short* __restrict__ faT_lo,
    unsigned short* __restrict__ fbT_hi, unsigned short* __restrict__ fbT_lo) {
    __shared__ float tile[64][68];
    int which = blockIdx.z;
    const float* src = which ? fb : fa;
    unsigned short* dhi = which ? fbT_hi : faT_hi;
    unsigned short* dlo = which ? fbT_lo : faT_lo;
    int p0 = blockIdx.x * 64;
    int c0 = blockIdx.y * 64;
    int t = threadIdx.x;
    {
        int c_r = t >> 2, seg = t & 3;
        const float* s = &src[(size_t)(c0 + c_r) * HW + p0 + seg * 16];
#pragma unroll
        for (int k = 0; k < 4; ++k)
            *(float4*)&tile[c_r][seg * 16 + k * 4] = *(const float4*)&s[k * 4];
    }
    __syncthreads();
    {
        int p_r = t >> 2, seg = t & 3;
        int cl = seg * 16;
        float rinv = rsqrtf(ssq[which * HW + p0 + p_r]);
        union { unsigned short us[8]; uint4 v; } h0, h1, l0, l1;
#pragma unroll
        for (int j = 0; j < 8; ++j) {
            float v = (tile[cl + j][p_r] - mu[which * CC + c0 + cl + j]) * rinv;
            unsigned short hi = f2bf(v);
            h0.us[j] = hi;
            l0.us[j] = f2bf(v - bf2f(hi));
        }
#pragma unroll
        for (int j = 0; j < 8; ++j) {
            float v = (tile[cl + 8 + j][p_r] - mu[which * CC + c0 + cl + 8 + j]) * rinv;
            unsigned short hi = f2bf(v);
            h1.us[j] = hi;
            l1.us[j] = f2bf(v - bf2f(hi));
        }
        size_t base = (size_t)(p0 + p_r) * CC + c0 + cl;
        *(uint4*)&dhi[base] = h0.v;
        *(uint4*)&dhi[base + 8] = h1.v;
        *(uint4*)&dlo[base] = l0.v;
        *(uint4*)&dlo[base + 8] = l1.v;
    }
}

// nearest-downsampled parse masks (channels 1..3), norm_a = max(sum_k mask_a, 1)
__global__ void k_masks(const int* __restrict__ fa_parse, const int* __restrict__ fb_parse,
                        float* __restrict__ mask_a, float* __restrict__ mask_b,
                        float* __restrict__ norm_a) {
    int p = blockIdx.x * 256 + threadIdx.x;
    int j = p >> 6, i = p & 63;
    int off = (4 * j) * 256 + 4 * i;   // nearest: src = 4*dst
    float s = 0.f;
    for (int k = 0; k < 3; ++k) {
        float a = (fa_parse[(k + 1) * 65536 + off] != 0) ? 1.f : 0.f;
        float b = (fb_parse[(k + 1) * 65536 + off] != 0) ? 1.f : 0.f;
        mask_a[k * HW + p] = a;
        mask_b[k * HW + p] = b;
        s += a;
    }
    norm_a[p] = fmaxf(s, 1.f);
}

// bilinear align_corners 256->64 of unalign_fb -> ufb[c2][hw]
__global__ void k_bilin_down(const float* __restrict__ src, float* __restrict__ ufb) {
    int p = blockIdx.x * 256 + threadIdx.x;
    int c = blockIdx.y;
    int j = p >> 6, i = p & 63;
    float ry = j * (255.0f / 63.0f);
    int y0 = (int)ry; y0 = min(y0, 255); int y1 = min(y0 + 1, 255);
    float wy = ry - (float)y0;
    float rx = i * (255.0f / 63.0f);
    int x0 = (int)rx; x0 = min(x0, 255); int x1 = min(x0 + 1, 255);
    float wx = rx - (float)x0;
    const float* sc = src + c * 65536;
    float r0 = sc[y0 * 256 + x0] * (1.f - wx) + sc[y0 * 256 + x1] * wx;
    float r1 = sc[y1 * 256 + x0] * (1.f - wx) + sc[y1 * 256 + x1] * wx;
    ufb[c * HW + p] = r0 * (1.f - wy) + r1 * wy;
}

// vtT[m][q] bf16, m = k*65 + c2 : (c2<64 -> mask_b*ufb, c2==64 -> mask_b), rows 195..255 zero
__global__ void k_build_vtT(const float* __restrict__ ufb, const float* __restrict__ mask_b,
                            unsigned short* __restrict__ vtT) {
    int q = blockIdx.x * 256 + threadIdx.x;
    int m = blockIdx.y;
    float v = 0.f;
    if (m < 195) {
        int k = m / 65, c2 = m % 65;
        float base = (c2 < 64) ? ufb[c2 * HW + q] : 1.0f;
        v = base * mask_b[k * HW + q];
    }
    vtT[(size_t)m * HW + q] = f2bf(v);
}

// bg[r] = sum_q (1-mask_b[k][q]) * (c2<64 ? ufb[c2][q] : 1)
__global__ void k_bg(const float* __restrict__ ufb, const float* __restrict__ mask_b,
                     float* __restrict__ bg) {
    __shared__ float sbuf[256];
    int r = blockIdx.x;
    int k = r / 65, c2 = r % 65;
    float s = 0.f;
    for (int q = threadIdx.x; q < HW; q += 256) {
        float base = (c2 < 64) ? ufb[c2 * HW + q] : 1.0f;
        s += base * (1.0f - mask_b[k * HW + q]);
    }
    float tot = block_reduce_sum_256(s, sbuf);
    if (threadIdx.x == 0) bg[r] = tot;
}

// E[p][q] = exp(100*S - 50) bf16, S = fanT(p,:) . fbnT(q,:), split-bf16 MFMA
// 128p x 128q tile, K=256, BK=64; 4 waves each 64x64 quadrant (4x4 MFMA tiles)
__global__ __launch_bounds__(256) void k_gemm_s_exp(
    const unsigned short* __restrict__ faT_hi, const unsigned short* __restrict__ faT_lo,
    const unsigned short* __restrict__ fbT_hi, const unsigned short* __restrict__ fbT_lo,
    unsigned short* __restrict__ E) {
    __shared__ union {
        struct { unsigned short Ah[128][72], Al[128][72], Bh[128][72], Bl[128][72]; } s;
        unsigned short ET[128][136];
    } sm;
    int t = threadIdx.x;
    int qbase = blockIdx.x * 128;
    int pbase = blockIdx.y * 128;
    int w = t >> 6, lane = t & 63, lr = lane & 15, quad = lane >> 4;
    int pw = (w & 1) * 64, qw = (w >> 1) * 64;
    int srow = t >> 3, sli = (t & 7) * 8;
    f32x4 acc[4][4] = {};

    for (int kt = 0; kt < 4; ++kt) {
        int cb = kt * 64;
        __syncthreads();
#pragma unroll
        for (int ps = 0; ps < 4; ++ps) {
            int r = srow + ps * 32;
            *(uint4*)&sm.s.Ah[r][sli] = *(const uint4*)&faT_hi[(size_t)(pbase + r) * CC + cb + sli];
            *(uint4*)&sm.s.Al[r][sli] = *(const uint4*)&faT_lo[(size_t)(pbase + r) * CC + cb + sli];
            *(uint4*)&sm.s.Bh[r][sli] = *(const uint4*)&fbT_hi[(size_t)(qbase + r) * CC + cb + sli];
            *(uint4*)&sm.s.Bl[r][sli] = *(const uint4*)&fbT_lo[(size_t)(qbase + r) * CC + cb + sli];
        }
        __syncthreads();
#pragma unroll
        for (int ks = 0; ks < 2; ++ks) {
            int ko = ks * 32 + quad * 8;
            bf8 ah[4], al[4], bh[4], bl[4];
#pragma unroll
            for (int i = 0; i < 4; ++i) {
                ah[i] = *(const bf8*)&sm.s.Ah[pw + 16 * i + lr][ko];
                al[i] = *(const bf8*)&sm.s.Al[pw + 16 * i + lr][ko];
            }
#pragma unroll
            for (int j = 0; j < 4; ++j) {
                bh[j] = *(const bf8*)&sm.s.Bh[qw + 16 * j + lr][ko];
                bl[j] = *(const bf8*)&sm.s.Bl[qw + 16 * j + lr][ko];
            }
#pragma unroll
            for (int i = 0; i < 4; ++i)
#pragma unroll
                for (int j = 0; j < 4; ++j) {
                    acc[i][j] = __builtin_amdgcn_mfma_f32_16x16x32_bf16(ah[i], bh[j], acc[i][j], 0, 0, 0);
                    acc[i][j] = __builtin_amdgcn_mfma_f32_16x16x32_bf16(ah[i], bl[j], acc[i][j], 0, 0, 0);
                    acc[i][j] = __builtin_amdgcn_mfma_f32_16x16x32_bf16(al[i], bh[j], acc[i][j], 0, 0, 0);
                }
        }
    }
    __syncthreads();
    // epilogue: exp + bf16, repack via LDS for coalesced stores
#pragma unroll
    for (int i = 0; i < 4; ++i) {
        int prow = pw + 16 * i + quad * 4;
#pragma unroll
        for (int j = 0; j < 4; ++j) {
            int qcol = qw + 16 * j + lr;
#pragma unroll
            for (int r = 0; r < 4; ++r) {
                float e = __expf(fmaf(100.f, acc[i][j][r], -50.f));
                sm.ET[prow + r][qcol] = f2bf(e);
            }
        }
    }
    __syncthreads();
    {
        int row = t >> 1, seg = t & 1;
        uint4* dst = (uint4*)&E[(size_t)(pbase + row) * HW + qbase + seg * 64];
        const uint4* src = (const uint4*)&sm.ET[row][seg * 64];
#pragma unroll
        for (int k = 0; k < 8; ++k) dst[k] = src[k];
    }
}

// part[z][m][p] = sum_{q in z-chunk} vtT[m][q] * E[p][q], bf16 MFMA
// 128m x 128p tile, K-chunk=512, BK=64
__global__ __launch_bounds__(256) void k_pv(
    const unsigned short* __restrict__ vtT, const unsigned short* __restrict__ E,
    float* __restrict__ part) {
    __shared__ struct { unsigned short Am[128][72], Bp[128][72]; } sm;
    int t = threadIdx.x;
    int pbase = blockIdx.x * 128;
    int mbase = blockIdx.y * 128;
    int z = blockIdx.z;
    int qz = z * 512;
    int w = t >> 6, lane = t & 63, lr = lane & 15, quad = lane >> 4;
    int mw = (w & 1) * 64, pw = (w >> 1) * 64;
    int srow = t >> 3, sli = (t & 7) * 8;
    f32x4 acc[4][4] = {};

    for (int kt = 0; kt < 8; ++kt) {
        int qo = qz + kt * 64;
        __syncthreads();
#pragma unroll
        for (int ps = 0; ps < 4; ++ps) {
            int r = srow + ps * 32;
            *(uint4*)&sm.Am[r][sli] = *(const uint4*)&vtT[(size_t)(mbase + r) * HW + qo + sli];
            *(uint4*)&sm.Bp[r][sli] = *(const uint4*)&E[(size_t)(pbase + r) * HW + qo + sli];
        }
        __syncthreads();
#pragma unroll
        for (int ks = 0; ks < 2; ++ks) {
            int ko = ks * 32 + quad * 8;
            bf8 a[4], b[4];
#pragma unroll
            for (int i = 0; i < 4; ++i) a[i] = *(const bf8*)&sm.Am[mw + 16 * i + lr][ko];
#pragma unroll
            for (int j = 0; j < 4; ++j) b[j] = *(const bf8*)&sm.Bp[pw + 16 * j + lr][ko];
#pragma unroll
            for (int i = 0; i < 4; ++i)
#pragma unroll
                for (int j = 0; j < 4; ++j)
                    acc[i][j] = __builtin_amdgcn_mfma_f32_16x16x32_bf16(a[i], b[j], acc[i][j], 0, 0, 0);
        }
    }
    float* op = part + (size_t)z * 1048576;
#pragma unroll
    for (int i = 0; i < 4; ++i) {
        int mrow = mbase + mw + 16 * i + quad * 4;
#pragma unroll
        for (int j = 0; j < 4; ++j) {
            int pcol = pbase + pw + 16 * j + lr;
#pragma unroll
            for (int r = 0; r < 4; ++r)
                op[(size_t)(mrow + r) * HW + pcol] = acc[i][j][r];
        }
    }
}

// part[0] = sum over 8 z-slices
__global__ void k_reduce8(float* __restrict__ part) {
    int i = (blockIdx.x * 256 + threadIdx.x) * 4;
    float4 s = *(float4*)&part[i];
    for (int z = 1; z < 8; ++z) {
        float4 b = *(float4*)&part[(size_t)z * 1048576 + i];
        s.x += b.x; s.y += b.y; s.z += b.z; s.w += b.w;
    }
    *(float4*)&part[i] = s;
}

// aligned[c2][p] = sum_k mask_a * (num + e50*bg_num)/(den + e50*bg_den) / norm_a
__global__ void k_combine(const float* __restrict__ acc_g, const float* __restrict__ bg,
                          const float* __restrict__ mask_a, const float* __restrict__ norm_a,
                          float* __restrict__ aligned) {
    int p = blockIdx.x * 256 + threadIdx.x;
    int c2 = blockIdx.y;
    float num = 0.f;
    for (int k = 0; k < 3; ++k) {
        float ma = mask_a[k * HW + p];
        float l  = acc_g[(k * 65 + 64) * HW + p] + E50f * bg[k * 65 + 64];
        float nu = acc_g[(k * 65 + c2) * HW + p] + E50f * bg[k * 65 + c2];
        num += ma * (nu / l);
    }
    aligned[c2 * HW + p] = num / norm_a[p];
}

// bilinear align_corners 64->256
__global__ void k_bilin_up(const float* __restrict__ aligned, float* __restrict__ out) {
    int idx = blockIdx.x * 256 + threadIdx.x;   // 0..65535
    int c2 = blockIdx.y;
    int y = idx >> 8, x = idx & 255;
    float ry = y * (63.0f / 255.0f);
    int y0 = (int)ry; y0 = min(y0, 63); int y1 = min(y0 + 1, 63);
    float wy = ry - (float)y0;
    float rx = x * (63.0f / 255.0f);
    int x0 = (int)rx; x0 = min(x0, 63); int x1 = min(x0 + 1, 63);
    float wx = rx - (float)x0;
    const float* a = aligned + c2 * HW;
    float r0 = a[y0 * 64 + x0] * (1.f - wx) + a[y0 * 64 + x1] * wx;
    float r1 = a[y1 * 64 + x0] * (1.f - wx) + a[y1 * 64 + x1] * wx;
    out[c2 * 65536 + idx] = r0 * (1.f - wy) + r1 * wy;
}

extern "C" void kernel_launch(void* const* d_in, const int* in_sizes, int n_in,
                              void* d_out, int out_size, void* d_ws, size_t ws_size,
                              hipStream_t stream) {
    const float* unalign_fb = (const float*)d_in[0];   // (1,64,256,256)
    const float* fa         = (const float*)d_in[1];   // (1,256,64,64)
    const int*   fa_parse   = (const int*)d_in[2];     // (1,4,256,256)
    const float* fb         = (const float*)d_in[3];   // (1,256,64,64)
    const int*   fb_parse   = (const int*)d_in[4];     // (1,4,256,256)
    float* out = (float*)d_out;                         // (1,64,256,256)

    float* w = (float*)d_ws;
    float* mu      = w;                    // 512
    float* mask_a  = w + 512;              // 12288
    float* mask_b  = w + 12800;            // 12288
    float* norm_a  = w + 25088;            // 4096
    float* bg      = w + 29184;            // 256
    float* ssq     = w + 29440;            // 8192
    float* ufb     = w + 37632;            // 262144
    float* aligned = w + 299776;           // 262144
    float* part    = w + 561920;           // 8*1048576
    unsigned short* faT_hi = (unsigned short*)(w + 8950528);    // 4096x256 bf16
    unsigned short* faT_lo = (unsigned short*)(w + 9474816);
    unsigned short* fbT_hi = (unsigned short*)(w + 9999104);
    unsigned short* fbT_lo = (unsigned short*)(w + 10523392);
    unsigned short* vtT    = (unsigned short*)(w + 11047680);   // 256x4096 bf16
    unsigned short* Ebuf   = (unsigned short*)(w + 11571968);   // 4096x4096 bf16
    // total ~19.96M floats = ~80 MB

    k_channel_mean<<<dim3(512), dim3(256), 0, stream>>>(fa, fb, mu);
    hipMemsetAsync(ssq, 0, 2 * HW * sizeof(float), stream);
    k_norm_ss<<<dim3(16, 8, 2), dim3(256), 0, stream>>>(fa, fb, mu, ssq);
    k_norm_split_t<<<dim3(64, 4, 2), dim3(256), 0, stream>>>(fa, fb, mu, ssq,
                                                             faT_hi, faT_lo, fbT_hi, fbT_lo);
    k_masks<<<dim3(16), dim3(256), 0, stream>>>(fa_parse, fb_parse, mask_a, mask_b, norm_a);
    k_bilin_down<<<dim3(16, 64), dim3(256), 0, stream>>>(unalign_fb, ufb);
    k_build_vtT<<<dim3(16, 256), dim3(256), 0, stream>>>(ufb, mask_b, vtT);
    k_bg<<<dim3(195), dim3(256), 0, stream>>>(ufb, mask_b, bg);

    k_gemm_s_exp<<<dim3(32, 32), dim3(256), 0, stream>>>(faT_hi, faT_lo, fbT_hi, fbT_lo, Ebuf);
    k_pv<<<dim3(32, 2, 8), dim3(256), 0, stream>>>(vtT, Ebuf, part);

    k_reduce8<<<dim3(1024), dim3(256), 0, stream>>>(part);
    k_combine<<<dim3(16, 64), dim3(256), 0, stream>>>(part, bg, mask_a, norm_a, aligned);
    k_bilin_up<<<dim3(256, 64), dim3(256), 0, stream>>>(aligned, out);
}

// Round 4
// 166.733 us; speedup vs baseline: 2.9540x; 1.1850x over previous
//
#include <hip/hip_runtime.h>
#include <math.h>

#define HW 4096      // 64*64 feature locations
#define CC 256       // feature channels
#define C2 64        // value channels
#define E50f 1.928749848e-22f   // expf(-50)

typedef unsigned short USH;
typedef __attribute__((ext_vector_type(8))) short bf8;
typedef __attribute__((ext_vector_type(4))) float f32x4;

__device__ __forceinline__ USH f2bf(float x) {
    unsigned u = __float_as_uint(x);
    u += 0x7fff + ((u >> 16) & 1);   // round-to-nearest-even
    return (USH)(u >> 16);
}
__device__ __forceinline__ float bf2f(USH h) {
    return __uint_as_float(((unsigned)h) << 16);
}

// async global->LDS DMA, 16B per lane; l must be wave-uniform
__device__ __forceinline__ void gl2lds16(const USH* g, USH* l) {
    __builtin_amdgcn_global_load_lds(
        (const __attribute__((address_space(1))) void*)g,
        (__attribute__((address_space(3))) void*)l, 16, 0, 0);
}

__device__ __forceinline__ float block_reduce_sum_256(float v, float* sbuf) {
    int t = threadIdx.x;
    sbuf[t] = v;
    __syncthreads();
    for (int s = 128; s > 0; s >>= 1) {
        if (t < s) sbuf[t] += sbuf[t + s];
        __syncthreads();
    }
    float r = sbuf[0];
    __syncthreads();
    return r;
}

// mu[0..255]=mean(fa[c]), mu[256..511]=mean(fb[c])
__global__ void k_channel_mean(const float* __restrict__ fa, const float* __restrict__ fb,
                               float* __restrict__ mu) {
    __shared__ float sbuf[256];
    int b = blockIdx.x;
    const float* src = (b < CC) ? (fa + b * HW) : (fb + (b - CC) * HW);
    float s = 0.f;
    for (int q = threadIdx.x; q < HW; q += 256) s += src[q];
    float tot = block_reduce_sum_256(s, sbuf);
    if (threadIdx.x == 0) mu[b] = tot * (1.0f / HW);
}

// partial sum of squares over 32-channel chunks -> ssq_part[which][8][4096]
__global__ void k_norm_ss(const float* __restrict__ fa, const float* __restrict__ fb,
                          const float* __restrict__ mu, float* __restrict__ ssq_part) {
    int which = blockIdx.z;
    const float* src = which ? fb : fa;
    int p = blockIdx.x * 256 + threadIdx.x;
    int c0 = blockIdx.y * 32;
    float ss = 0.f;
    for (int c = c0; c < c0 + 32; ++c) {
        float v = src[c * HW + p] - mu[which * CC + c];
        ss += v * v;
    }
    ssq_part[(which * 8 + blockIdx.y) * HW + p] = ss;
}

// fused: center + L2-normalize + hi/lo bf16 split + transpose into chunked
// layout [kc][p][32] (kc = c/32) for contiguous BK=32 GEMM staging
__global__ __launch_bounds__(256) void k_norm_split_t(
    const float* __restrict__ fa, const float* __restrict__ fb,
    const float* __restrict__ mu, const float* __restrict__ ssq_part,
    USH* __restrict__ faT_hi, USH* __restrict__ faT_lo,
    USH* __restrict__ fbT_hi, USH* __restrict__ fbT_lo) {
    __shared__ float tile[64][68];
    int which = blockIdx.z;
    const float* src = which ? fb : fa;
    USH* dhi = which ? fbT_hi : faT_hi;
    USH* dlo = which ? fbT_lo : faT_lo;
    int p0 = blockIdx.x * 64;
    int c0 = blockIdx.y * 64;
    int t = threadIdx.x;
    {
        int c_r = t >> 2, seg = t & 3;
        const float* s = &src[(size_t)(c0 + c_r) * HW + p0 + seg * 16];
#pragma unroll
        for (int k = 0; k < 4; ++k)
            *(float4*)&tile[c_r][seg * 16 + k * 4] = *(const float4*)&s[k * 4];
    }
    __syncthreads();
    {
        int p_r = t >> 2, seg = t & 3;
        int cl = seg * 16;
        float ss = 0.f;
#pragma unroll
        for (int z = 0; z < 8; ++z) ss += ssq_part[(which * 8 + z) * HW + p0 + p_r];
        float rinv = rsqrtf(ss);
        union { USH us[8]; uint4 v; } h0, h1, l0, l1;
#pragma unroll
        for (int j = 0; j < 8; ++j) {
            float v = (tile[cl + j][p_r] - mu[which * CC + c0 + cl + j]) * rinv;
            USH hi = f2bf(v);
            h0.us[j] = hi;
            l0.us[j] = f2bf(v - bf2f(hi));
        }
#pragma unroll
        for (int j = 0; j < 8; ++j) {
            float v = (tile[cl + 8 + j][p_r] - mu[which * CC + c0 + cl + 8 + j]) * rinv;
            USH hi = f2bf(v);
            h1.us[j] = hi;
            l1.us[j] = f2bf(v - bf2f(hi));
        }
        int kc = (c0 >> 5) + (seg >> 1);
        size_t base = (size_t)kc * 131072 + (size_t)(p0 + p_r) * 32 + (seg & 1) * 16;
        *(uint4*)&dhi[base] = h0.v;
        *(uint4*)&dhi[base + 8] = h1.v;
        *(uint4*)&dlo[base] = l0.v;
        *(uint4*)&dlo[base + 8] = l1.v;
    }
}

// parse masks + norm_a + zero tot[64]
__global__ void k_masks(const int* __restrict__ fa_parse, const int* __restrict__ fb_parse,
                        float* __restrict__ mask_a, float* __restrict__ mask_b,
                        float* __restrict__ norm_a, float* __restrict__ tot) {
    int t = threadIdx.x;
    if (blockIdx.x == 0 && t < 64) tot[t] = 0.f;
    int p = blockIdx.x * 256 + t;
    int j = p >> 6, i = p & 63;
    int off = (4 * j) * 256 + 4 * i;   // nearest: src = 4*dst
    float s = 0.f;
    for (int k = 0; k < 3; ++k) {
        float a = (fa_parse[(k + 1) * 65536 + off] != 0) ? 1.f : 0.f;
        float b = (fb_parse[(k + 1) * 65536 + off] != 0) ? 1.f : 0.f;
        mask_a[k * HW + p] = a;
        mask_b[k * HW + p] = b;
        s += a;
    }
    norm_a[p] = fmaxf(s, 1.f);
}

// bilinear 256->64 of unalign_fb fused with vtT build (rows m=k*65+c2, chunked
// layout [qc][m][32]) and per-channel totals (for bg)
__global__ void k_bilin_down_vt(const float* __restrict__ src, const float* __restrict__ mask_b,
                                USH* __restrict__ vtT, float* __restrict__ tot) {
    __shared__ float sbuf[256];
    int p = blockIdx.x * 256 + threadIdx.x;
    int c = blockIdx.y;
    int j = p >> 6, i = p & 63;
    float ry = j * (255.0f / 63.0f);
    int y0 = (int)ry; y0 = min(y0, 255); int y1 = min(y0 + 1, 255);
    float wy = ry - (float)y0;
    float rx = i * (255.0f / 63.0f);
    int x0 = (int)rx; x0 = min(x0, 255); int x1 = min(x0 + 1, 255);
    float wx = rx - (float)x0;
    const float* sc = src + c * 65536;
    float r0 = sc[y0 * 256 + x0] * (1.f - wx) + sc[y0 * 256 + x1] * wx;
    float r1 = sc[y1 * 256 + x0] * (1.f - wx) + sc[y1 * 256 + x1] * wx;
    float v = r0 * (1.f - wy) + r1 * wy;
    size_t cbase = (size_t)(p >> 5) * 8192 + (p & 31);
#pragma unroll
    for (int k = 0; k < 3; ++k)
        vtT[cbase + (k * 65 + c) * 32] = f2bf(v * mask_b[k * HW + p]);
    float bt = block_reduce_sum_256(v, sbuf);
    if (threadIdx.x == 0) atomicAdd(&tot[c], bt);
}

// vtT rows m=65k+64 (mask rows) and zero rows 195..255
__global__ void k_vt_rest(const float* __restrict__ mask_b, USH* __restrict__ vtT) {
    int p = blockIdx.x * 256 + threadIdx.x;
    int my = blockIdx.y;
    int m; float v;
    if (my < 3) { m = 65 * my + 64; v = mask_b[my * HW + p]; }
    else        { m = 192 + my;     v = 0.f; }
    vtT[(size_t)(p >> 5) * 8192 + m * 32 + (p & 31)] = f2bf(v);
}

// bg[m] = (c2<64 ? tot[c2] : 4096) - rowsum(vtT[m])
__global__ void k_bg2(const USH* __restrict__ vtT, const float* __restrict__ tot,
                      float* __restrict__ bg) {
    __shared__ float sbuf[256];
    int m = blockIdx.x;
    int t = threadIdx.x;
    size_t base = (size_t)(t >> 1) * 8192 + m * 32 + (t & 1) * 16;
    union { uint4 v; USH us[8]; } a, b;
    a.v = *(const uint4*)&vtT[base];
    b.v = *(const uint4*)&vtT[base + 8];
    float s = 0.f;
#pragma unroll
    for (int j = 0; j < 8; ++j) s += bf2f(a.us[j]) + bf2f(b.us[j]);
    float rsum = block_reduce_sum_256(s, sbuf);
    if (t == 0) {
        int c2 = m % 65;
        bg[m] = ((c2 < 64) ? tot[c2] : 4096.0f) - rsum;
    }
}

// E[p][q] = exp(100*S - 50) bf16 in chunked layout [qc][p][32]
// S = fa(p)·fb(q) via split-bf16 (3-term) MFMA. 128p x 128q tile, BK=32,
// double-buffered LDS fed by global_load_lds DMA issued one kt ahead.
__global__ __launch_bounds__(256) void k_gemm_s_exp(
    const USH* __restrict__ faT_hi, const USH* __restrict__ faT_lo,
    const USH* __restrict__ fbT_hi, const USH* __restrict__ fbT_lo,
    USH* __restrict__ E) {
    __shared__ union { USH stage[2][4][4096]; USH ET[128][136]; } sm;
    int t = threadIdx.x;
    int qbase = blockIdx.x * 128;
    int pbase = blockIdx.y * 128;
    int w = t >> 6, lane = t & 63, lr = lane & 15, quad = lane >> 4;
    int pw = (w & 1) * 64, qw = (w >> 1) * 64;
    f32x4 acc[4][4] = {};

    const USH* srcA_h = faT_hi + (size_t)pbase * 32;
    const USH* srcA_l = faT_lo + (size_t)pbase * 32;
    const USH* srcB_h = fbT_hi + (size_t)qbase * 32;
    const USH* srcB_l = fbT_lo + (size_t)qbase * 32;

#define STAGE_G(buf, kt)                                                        \
    {                                                                           \
        size_t ko = (size_t)(kt) * 131072;                                      \
        _Pragma("unroll")                                                       \
        for (int c = 0; c < 2; ++c) {                                           \
            int go = w * 1024 + c * 512 + lane * 8;                             \
            int lo = w * 1024 + c * 512;                                        \
            gl2lds16(srcA_h + ko + go, &sm.stage[buf][0][lo]);                  \
            gl2lds16(srcA_l + ko + go, &sm.stage[buf][1][lo]);                  \
            gl2lds16(srcB_h + ko + go, &sm.stage[buf][2][lo]);                  \
            gl2lds16(srcB_l + ko + go, &sm.stage[buf][3][lo]);                  \
        }                                                                       \
    }

    STAGE_G(0, 0);
    __syncthreads();
    for (int kt = 0; kt < 8; ++kt) {
        int cur = kt & 1;
        if (kt + 1 < 8) STAGE_G(cur ^ 1, kt + 1);
        bf8 ah[4], al[4], bh[4], bl[4];
#pragma unroll
        for (int i = 0; i < 4; ++i) {
            ah[i] = *(const bf8*)&sm.stage[cur][0][(pw + 16 * i + lr) * 32 + quad * 8];
            al[i] = *(const bf8*)&sm.stage[cur][1][(pw + 16 * i + lr) * 32 + quad * 8];
        }
#pragma unroll
        for (int j = 0; j < 4; ++j) {
            bh[j] = *(const bf8*)&sm.stage[cur][2][(qw + 16 * j + lr) * 32 + quad * 8];
            bl[j] = *(const bf8*)&sm.stage[cur][3][(qw + 16 * j + lr) * 32 + quad * 8];
        }
#pragma unroll
        for (int i = 0; i < 4; ++i)
#pragma unroll
            for (int j = 0; j < 4; ++j) {
                acc[i][j] = __builtin_amdgcn_mfma_f32_16x16x32_bf16(ah[i], bh[j], acc[i][j], 0, 0, 0);
                acc[i][j] = __builtin_amdgcn_mfma_f32_16x16x32_bf16(ah[i], bl[j], acc[i][j], 0, 0, 0);
                acc[i][j] = __builtin_amdgcn_mfma_f32_16x16x32_bf16(al[i], bh[j], acc[i][j], 0, 0, 0);
            }
        __syncthreads();
    }
#undef STAGE_G
    // epilogue: exp -> bf16, repack via LDS (union with stage bufs; all waves past barrier)
#pragma unroll
    for (int i = 0; i < 4; ++i) {
        int prow = pw + 16 * i + quad * 4;
#pragma unroll
        for (int j = 0; j < 4; ++j) {
            int qcol = qw + 16 * j + lr;
#pragma unroll
            for (int r = 0; r < 4; ++r)
                sm.ET[prow + r][qcol] = f2bf(__expf(fmaf(100.f, acc[i][j][r], -50.f)));
        }
    }
    __syncthreads();
    {
        int prow = t >> 1, half = t & 1;
#pragma unroll
        for (int cc = 0; cc < 2; ++cc) {
            int qcl = half * 2 + cc;                       // local 32-chunk of q
            size_t dst = (size_t)((qbase >> 5) + qcl) * 131072 + (size_t)(pbase + prow) * 32;
#pragma unroll
            for (int u = 0; u < 4; ++u)
                *(uint4*)&E[dst + u * 8] = *(const uint4*)&sm.ET[prow][qcl * 32 + u * 8];
        }
    }
}

// part[z][m][p] = sum_{q in z-chunk(512)} vtT[m][q] * E[p][q], bf16 MFMA
// 128m x 128p tile, BK=32, dbuf + async DMA
__global__ __launch_bounds__(256) void k_pv(
    const USH* __restrict__ vtT, const USH* __restrict__ E,
    float* __restrict__ part) {
    __shared__ USH stage[2][2][4096];
    int t = threadIdx.x;
    int pbase = blockIdx.x * 128;
    int mbase = blockIdx.y * 128;
    int z = blockIdx.z;
    int w = t >> 6, lane = t & 63, lr = lane & 15, quad = lane >> 4;
    int mw = (w & 1) * 64, pw = (w >> 1) * 64;
    f32x4 acc[4][4] = {};

    const USH* srcA = vtT + (size_t)mbase * 32;
    const USH* srcB = E + (size_t)pbase * 32;

#define STAGE_P(buf, kt)                                                        \
    {                                                                           \
        size_t koA = (size_t)(z * 16 + (kt)) * 8192;                            \
        size_t koB = (size_t)(z * 16 + (kt)) * 131072;                          \
        _Pragma("unroll")                                                       \
        for (int c = 0; c < 2; ++c) {                                           \
            int go = w * 1024 + c * 512 + lane * 8;                             \
            int lo = w * 1024 + c * 512;                                        \
            gl2lds16(srcA + koA + go, &stage[buf][0][lo]);                      \
            gl2lds16(srcB + koB + go, &stage[buf][1][lo]);                      \
        }                                                                       \
    }

    STAGE_P(0, 0);
    __syncthreads();
    for (int kt = 0; kt < 16; ++kt) {
        int cur = kt & 1;
        if (kt + 1 < 16) STAGE_P(cur ^ 1, kt + 1);
        bf8 a[4], b[4];
#pragma unroll
        for (int i = 0; i < 4; ++i)
            a[i] = *(const bf8*)&stage[cur][0][(mw + 16 * i + lr) * 32 + quad * 8];
#pragma unroll
        for (int j = 0; j < 4; ++j)
            b[j] = *(const bf8*)&stage[cur][1][(pw + 16 * j + lr) * 32 + quad * 8];
#pragma unroll
        for (int i = 0; i < 4; ++i)
#pragma unroll
            for (int j = 0; j < 4; ++j)
                acc[i][j] = __builtin_amdgcn_mfma_f32_16x16x32_bf16(a[i], b[j], acc[i][j], 0, 0, 0);
        __syncthreads();
    }
#undef STAGE_P
    float* op = part + (size_t)z * 1048576;
#pragma unroll
    for (int i = 0; i < 4; ++i) {
        int mrow = mbase + mw + 16 * i + quad * 4;
#pragma unroll
        for (int j = 0; j < 4; ++j) {
            int pcol = pbase + pw + 16 * j + lr;
#pragma unroll
            for (int r = 0; r < 4; ++r)
                op[(size_t)(mrow + r) * HW + pcol] = acc[i][j][r];
        }
    }
}

// aligned[c2][p] = sum_k mask_a*(num+e50*bgn)/(den+e50*bgd)/norm_a, summing 8 z-slices inline
__global__ void k_combine8(const float* __restrict__ part, const float* __restrict__ bg,
                           const float* __restrict__ mask_a, const float* __restrict__ norm_a,
                           float* __restrict__ aligned) {
    int p = blockIdx.x * 256 + threadIdx.x;
    int c2 = blockIdx.y;
    float num = 0.f;
    for (int k = 0; k < 3; ++k) {
        float ma = mask_a[k * HW + p];
        float den = E50f * bg[k * 65 + 64];
        float nu  = E50f * bg[k * 65 + c2];
        size_t rd = (size_t)(k * 65 + 64) * HW + p;
        size_t rn = (size_t)(k * 65 + c2) * HW + p;
#pragma unroll
        for (int z = 0; z < 8; ++z) {
            den += part[(size_t)z * 1048576 + rd];
            nu  += part[(size_t)z * 1048576 + rn];
        }
        num += ma * (nu / den);
    }
    aligned[c2 * HW + p] = num / norm_a[p];
}

// bilinear align_corners 64->256, 4 outputs per thread (float4 stores)
__global__ void k_bilin_up(const float* __restrict__ aligned, float* __restrict__ out) {
    int idx = (blockIdx.x * 256 + threadIdx.x) * 4;   // 0..65532
    int c2 = blockIdx.y;
    int y = idx >> 8;
    float ry = y * (63.0f / 255.0f);
    int y0 = (int)ry; y0 = min(y0, 63); int y1 = min(y0 + 1, 63);
    float wy = ry - (float)y0;
    const float* a = aligned + c2 * HW;
    float4 o;
    float* op = &o.x;
#pragma unroll
    for (int u = 0; u < 4; ++u) {
        int x = (idx & 255) + u;
        float rx = x * (63.0f / 255.0f);
        int x0 = (int)rx; x0 = min(x0, 63); int x1 = min(x0 + 1, 63);
        float wx = rx - (float)x0;
        float r0 = a[y0 * 64 + x0] * (1.f - wx) + a[y0 * 64 + x1] * wx;
        float r1 = a[y1 * 64 + x0] * (1.f - wx) + a[y1 * 64 + x1] * wx;
        op[u] = r0 * (1.f - wy) + r1 * wy;
    }
    *(float4*)&out[c2 * 65536 + idx] = o;
}

extern "C" void kernel_launch(void* const* d_in, const int* in_sizes, int n_in,
                              void* d_out, int out_size, void* d_ws, size_t ws_size,
                              hipStream_t stream) {
    const float* unalign_fb = (const float*)d_in[0];   // (1,64,256,256)
    const float* fa         = (const float*)d_in[1];   // (1,256,64,64)
    const int*   fa_parse   = (const int*)d_in[2];     // (1,4,256,256)
    const float* fb         = (const float*)d_in[3];   // (1,256,64,64)
    const int*   fb_parse   = (const int*)d_in[4];     // (1,4,256,256)
    float* out = (float*)d_out;                         // (1,64,256,256)

    float* w = (float*)d_ws;
    float* mu       = w;                   // 512
    float* mask_a   = w + 512;             // 12288
    float* mask_b   = w + 12800;           // 12288
    float* norm_a   = w + 25088;           // 4096
    float* bg       = w + 29184;           // 256
    float* tot      = w + 29440;           // 64
    float* ssq_part = w + 29504;           // 2*8*4096 = 65536
    float* part     = w + 95040;           // 8*1048576
    float* aligned  = w + 8483648;         // 262144
    USH* faT_hi = (USH*)(w + 8745792);     // 4096x256 bf16 chunked [kc][p][32]
    USH* faT_lo = (USH*)(w + 9270080);
    USH* fbT_hi = (USH*)(w + 9794368);
    USH* fbT_lo = (USH*)(w + 10318656);
    USH* vtT    = (USH*)(w + 10842944);    // [qc][256m][32] bf16
    USH* Ebuf   = (USH*)(w + 11367232);    // [qc][4096p][32] bf16
    // total ~19.76M floats = ~79 MB

    k_channel_mean<<<dim3(512), dim3(256), 0, stream>>>(fa, fb, mu);
    k_norm_ss<<<dim3(16, 8, 2), dim3(256), 0, stream>>>(fa, fb, mu, ssq_part);
    k_norm_split_t<<<dim3(64, 4, 2), dim3(256), 0, stream>>>(fa, fb, mu, ssq_part,
                                                             faT_hi, faT_lo, fbT_hi, fbT_lo);
    k_masks<<<dim3(16), dim3(256), 0, stream>>>(fa_parse, fb_parse, mask_a, mask_b, norm_a, tot);
    k_bilin_down_vt<<<dim3(16, 64), dim3(256), 0, stream>>>(unalign_fb, mask_b, vtT, tot);
    k_vt_rest<<<dim3(16, 64), dim3(256), 0, stream>>>(mask_b, vtT);
    k_bg2<<<dim3(195), dim3(256), 0, stream>>>(vtT, tot, bg);

    k_gemm_s_exp<<<dim3(32, 32), dim3(256), 0, stream>>>(faT_hi, faT_lo, fbT_hi, fbT_lo, Ebuf);
    k_pv<<<dim3(32, 2, 8), dim3(256), 0, stream>>>(vtT, Ebuf, part);

    k_combine8<<<dim3(16, 64), dim3(256), 0, stream>>>(part, bg, mask_a, norm_a, aligned);
    k_bilin_up<<<dim3(64, 64), dim3(256), 0, stream>>>(aligned, out);
}

// Round 5
// 150.661 us; speedup vs baseline: 3.2691x; 1.1067x over previous
//
#include <hip/hip_runtime.h>
#include <math.h>

#define HW 4096      // 64*64 feature locations
#define CC 256       // feature channels
#define C2 64        // value channels
#define E50f 1.928749848e-22f   // expf(-50)

typedef unsigned short USH;
typedef __attribute__((ext_vector_type(8))) _Float16 f16x8;
typedef __attribute__((ext_vector_type(8))) short bf8;
typedef __attribute__((ext_vector_type(4))) float f32x4;

__device__ __forceinline__ USH f2bf(float x) {
    unsigned u = __float_as_uint(x);
    u += 0x7fff + ((u >> 16) & 1);   // round-to-nearest-even
    return (USH)(u >> 16);
}
__device__ __forceinline__ USH f2h(float x) {
    _Float16 h = (_Float16)x;        // v_cvt_f16_f32, RTNE
    return *(USH*)&h;
}

// async global->LDS DMA, 16B per lane; LDS base must be wave-uniform
__device__ __forceinline__ void gl2lds16(const USH* g, USH* l) {
    __builtin_amdgcn_global_load_lds(
        (const __attribute__((address_space(1))) void*)g,
        (__attribute__((address_space(3))) void*)l, 16, 0, 0);
}

__device__ __forceinline__ float block_reduce_sum_256(float v, float* sbuf) {
    int t = threadIdx.x;
    sbuf[t] = v;
    __syncthreads();
    for (int s = 128; s > 0; s >>= 1) {
        if (t < s) sbuf[t] += sbuf[t + s];
        __syncthreads();
    }
    float r = sbuf[0];
    __syncthreads();
    return r;
}

// mu[0..255]=mean(fa[c]), mu[256..511]=mean(fb[c])
__global__ void k_channel_mean(const float* __restrict__ fa, const float* __restrict__ fb,
                               float* __restrict__ mu) {
    __shared__ float sbuf[256];
    int b = blockIdx.x;
    const float* src = (b < CC) ? (fa + b * HW) : (fb + (b - CC) * HW);
    float s = 0.f;
    for (int q = threadIdx.x; q < HW; q += 256) s += src[q];
    float tot = block_reduce_sum_256(s, sbuf);
    if (threadIdx.x == 0) mu[b] = tot * (1.0f / HW);
}

// partial sum of squares over 32-channel chunks -> ssq_part[which][8][4096]
__global__ void k_norm_ss(const float* __restrict__ fa, const float* __restrict__ fb,
                          const float* __restrict__ mu, float* __restrict__ ssq_part) {
    int which = blockIdx.z;
    const float* src = which ? fb : fa;
    int p = blockIdx.x * 256 + threadIdx.x;
    int c0 = blockIdx.y * 32;
    float ss = 0.f;
    for (int c = c0; c < c0 + 32; ++c) {
        float v = src[c * HW + p] - mu[which * CC + c];
        ss += v * v;
    }
    ssq_part[(which * 8 + blockIdx.y) * HW + p] = ss;
}

// fused: center + L2-normalize + fp16 cast + transpose into chunked layout
// [kc][p][32] (kc = c/32) for contiguous BK=32 GEMM staging
__global__ __launch_bounds__(256) void k_norm_split_t(
    const float* __restrict__ fa, const float* __restrict__ fb,
    const float* __restrict__ mu, const float* __restrict__ ssq_part,
    USH* __restrict__ faT, USH* __restrict__ fbT) {
    __shared__ float tile[64][68];
    int which = blockIdx.z;
    const float* src = which ? fb : fa;
    USH* dst = which ? fbT : faT;
    int p0 = blockIdx.x * 64;
    int c0 = blockIdx.y * 64;
    int t = threadIdx.x;
    {
        int c_r = t >> 2, seg = t & 3;
        const float* s = &src[(size_t)(c0 + c_r) * HW + p0 + seg * 16];
#pragma unroll
        for (int k = 0; k < 4; ++k)
            *(float4*)&tile[c_r][seg * 16 + k * 4] = *(const float4*)&s[k * 4];
    }
    __syncthreads();
    {
        int p_r = t >> 2, seg = t & 3;
        int cl = seg * 16;
        float ss = 0.f;
#pragma unroll
        for (int z = 0; z < 8; ++z) ss += ssq_part[(which * 8 + z) * HW + p0 + p_r];
        float rinv = rsqrtf(ss);
        union { USH us[8]; uint4 v; } h0, h1;
#pragma unroll
        for (int j = 0; j < 8; ++j)
            h0.us[j] = f2h((tile[cl + j][p_r] - mu[which * CC + c0 + cl + j]) * rinv);
#pragma unroll
        for (int j = 0; j < 8; ++j)
            h1.us[j] = f2h((tile[cl + 8 + j][p_r] - mu[which * CC + c0 + cl + 8 + j]) * rinv);
        int kc = (c0 >> 5) + (seg >> 1);
        size_t base = (size_t)kc * 131072 + (size_t)(p0 + p_r) * 32 + (seg & 1) * 16;
        *(uint4*)&dst[base] = h0.v;
        *(uint4*)&dst[base + 8] = h1.v;
    }
}

// bilinear 256->64 of unalign_fb fused with: mask_b from fb_parse, full vtT
// build (value rows, mask rows, zero rows; chunked [qc][m][32]), and
// rowsum/tot accumulation for the bg algebra.
// bgbuf layout: [0..255] rowsum[m], [256..319] tot[c2]
__global__ void k_bilin_down_vt(const float* __restrict__ src, const int* __restrict__ fb_parse,
                                USH* __restrict__ vtT, float* __restrict__ bgbuf) {
    __shared__ float4 sbuf[256];
    int t = threadIdx.x;
    int p = blockIdx.x * 256 + t;
    int c = blockIdx.y;
    int j = p >> 6, i = p & 63;
    int off = (4 * j) * 256 + 4 * i;   // nearest: src = 4*dst
    float m0 = (fb_parse[1 * 65536 + off] != 0) ? 1.f : 0.f;
    float m1 = (fb_parse[2 * 65536 + off] != 0) ? 1.f : 0.f;
    float m2 = (fb_parse[3 * 65536 + off] != 0) ? 1.f : 0.f;
    float ry = j * (255.0f / 63.0f);
    int y0 = (int)ry; y0 = min(y0, 255); int y1 = min(y0 + 1, 255);
    float wy = ry - (float)y0;
    float rx = i * (255.0f / 63.0f);
    int x0 = (int)rx; x0 = min(x0, 255); int x1 = min(x0 + 1, 255);
    float wx = rx - (float)x0;
    const float* sc = src + c * 65536;
    float r0 = sc[y0 * 256 + x0] * (1.f - wx) + sc[y0 * 256 + x1] * wx;
    float r1 = sc[y1 * 256 + x0] * (1.f - wx) + sc[y1 * 256 + x1] * wx;
    float v = r0 * (1.f - wy) + r1 * wy;
    size_t cbase = (size_t)(p >> 5) * 8192 + (p & 31);
    vtT[cbase + (0 * 65 + c) * 32] = f2bf(v * m0);
    vtT[cbase + (1 * 65 + c) * 32] = f2bf(v * m1);
    vtT[cbase + (2 * 65 + c) * 32] = f2bf(v * m2);
    if (c == 0) {
        vtT[cbase + 64 * 32]  = f2bf(m0);
        vtT[cbase + 129 * 32] = f2bf(m1);
        vtT[cbase + 194 * 32] = f2bf(m2);
        for (int m = 195; m < 256; ++m) vtT[cbase + m * 32] = 0;
    }
    // block-reduce (v, v*m0, v*m1, v*m2)
    float4 acc = make_float4(v, v * m0, v * m1, v * m2);
    sbuf[t] = acc;
    __syncthreads();
    for (int s = 128; s > 0; s >>= 1) {
        if (t < s) {
            float4 o = sbuf[t + s];
            sbuf[t].x += o.x; sbuf[t].y += o.y; sbuf[t].z += o.z; sbuf[t].w += o.w;
        }
        __syncthreads();
    }
    if (t == 0) {
        float4 r = sbuf[0];
        atomicAdd(&bgbuf[256 + c], r.x);         // tot[c]
        atomicAdd(&bgbuf[0 * 65 + c], r.y);      // rowsum[m=c]
        atomicAdd(&bgbuf[1 * 65 + c], r.z);
        atomicAdd(&bgbuf[2 * 65 + c], r.w);
    }
    __syncthreads();
    if (c == 0) {   // mask-row sums (block-uniform branch)
        sbuf[t] = make_float4(m0, m1, m2, 0.f);
        __syncthreads();
        for (int s = 128; s > 0; s >>= 1) {
            if (t < s) {
                float4 o = sbuf[t + s];
                sbuf[t].x += o.x; sbuf[t].y += o.y; sbuf[t].z += o.z;
            }
            __syncthreads();
        }
        if (t == 0) {
            float4 r = sbuf[0];
            atomicAdd(&bgbuf[64], r.x);
            atomicAdd(&bgbuf[129], r.y);
            atomicAdd(&bgbuf[194], r.z);
        }
    }
}

// E[p][q] = exp(100*S - 50) bf16 in chunked layout [qc][p][32]
// S = fa(p)·fb(q), single-term fp16 MFMA. 128p x 128q tile, BK=32,
// double-buffered LDS fed by global_load_lds DMA issued one kt ahead.
__global__ __launch_bounds__(256) void k_gemm_s_exp(
    const USH* __restrict__ faT, const USH* __restrict__ fbT,
    USH* __restrict__ E) {
    __shared__ union { USH stage[2][2][4096]; USH ET[128][136]; } sm;
    int t = threadIdx.x;
    int qbase = blockIdx.x * 128;
    int pbase = blockIdx.y * 128;
    int w = t >> 6, lane = t & 63, lr = lane & 15, quad = lane >> 4;
    int pw = (w & 1) * 64, qw = (w >> 1) * 64;
    f32x4 acc[4][4] = {};

    const USH* srcA = faT + (size_t)pbase * 32;
    const USH* srcB = fbT + (size_t)qbase * 32;

#define STAGE_G(buf, kt)                                                        \
    {                                                                           \
        size_t ko = (size_t)(kt) * 131072;                                      \
        _Pragma("unroll")                                                       \
        for (int c = 0; c < 2; ++c) {                                           \
            int go = w * 1024 + c * 512 + lane * 8;                             \
            int lo = w * 1024 + c * 512;                                        \
            gl2lds16(srcA + ko + go, &sm.stage[buf][0][lo]);                    \
            gl2lds16(srcB + ko + go, &sm.stage[buf][1][lo]);                    \
        }                                                                       \
    }

    STAGE_G(0, 0);
    __syncthreads();
    for (int kt = 0; kt < 8; ++kt) {
        int cur = kt & 1;
        if (kt + 1 < 8) STAGE_G(cur ^ 1, kt + 1);
        f16x8 a[4], b[4];
#pragma unroll
        for (int i = 0; i < 4; ++i)
            a[i] = *(const f16x8*)&sm.stage[cur][0][(pw + 16 * i + lr) * 32 + quad * 8];
#pragma unroll
        for (int j = 0; j < 4; ++j)
            b[j] = *(const f16x8*)&sm.stage[cur][1][(qw + 16 * j + lr) * 32 + quad * 8];
#pragma unroll
        for (int i = 0; i < 4; ++i)
#pragma unroll
            for (int j = 0; j < 4; ++j)
                acc[i][j] = __builtin_amdgcn_mfma_f32_16x16x32_f16(a[i], b[j], acc[i][j], 0, 0, 0);
        __syncthreads();
    }
#undef STAGE_G
    // epilogue: exp -> bf16, repack via LDS (union with stage bufs; all waves past barrier)
#pragma unroll
    for (int i = 0; i < 4; ++i) {
        int prow = pw + 16 * i + quad * 4;
#pragma unroll
        for (int j = 0; j < 4; ++j) {
            int qcol = qw + 16 * j + lr;
#pragma unroll
            for (int r = 0; r < 4; ++r)
                sm.ET[prow + r][qcol] = f2bf(__expf(fmaf(100.f, acc[i][j][r], -50.f)));
        }
    }
    __syncthreads();
    {
        int prow = t >> 1, half = t & 1;
#pragma unroll
        for (int cc = 0; cc < 2; ++cc) {
            int qcl = half * 2 + cc;                       // local 32-chunk of q
            size_t dst = (size_t)((qbase >> 5) + qcl) * 131072 + (size_t)(pbase + prow) * 32;
#pragma unroll
            for (int u = 0; u < 4; ++u)
                *(uint4*)&E[dst + u * 8] = *(const uint4*)&sm.ET[prow][qcl * 32 + u * 8];
        }
    }
}

// part[z][m][p] = sum_{q in z-chunk(512)} vtT[m][q] * E[p][q], bf16 MFMA
// 128m x 128p tile, BK=32, dbuf + async DMA
__global__ __launch_bounds__(256) void k_pv(
    const USH* __restrict__ vtT, const USH* __restrict__ E,
    float* __restrict__ part) {
    __shared__ USH stage[2][2][4096];
    int t = threadIdx.x;
    int pbase = blockIdx.x * 128;
    int mbase = blockIdx.y * 128;
    int z = blockIdx.z;
    int w = t >> 6, lane = t & 63, lr = lane & 15, quad = lane >> 4;
    int mw = (w & 1) * 64, pw = (w >> 1) * 64;
    f32x4 acc[4][4] = {};

    const USH* srcA = vtT + (size_t)mbase * 32;
    const USH* srcB = E + (size_t)pbase * 32;

#define STAGE_P(buf, kt)                                                        \
    {                                                                           \
        size_t koA = (size_t)(z * 16 + (kt)) * 8192;                            \
        size_t koB = (size_t)(z * 16 + (kt)) * 131072;                          \
        _Pragma("unroll")                                                       \
        for (int c = 0; c < 2; ++c) {                                           \
            int go = w * 1024 + c * 512 + lane * 8;                             \
            int lo = w * 1024 + c * 512;                                        \
            gl2lds16(srcA + koA + go, &stage[buf][0][lo]);                      \
            gl2lds16(srcB + koB + go, &stage[buf][1][lo]);                      \
        }                                                                       \
    }

    STAGE_P(0, 0);
    __syncthreads();
    for (int kt = 0; kt < 16; ++kt) {
        int cur = kt & 1;
        if (kt + 1 < 16) STAGE_P(cur ^ 1, kt + 1);
        bf8 a[4], b[4];
#pragma unroll
        for (int i = 0; i < 4; ++i)
            a[i] = *(const bf8*)&stage[cur][0][(mw + 16 * i + lr) * 32 + quad * 8];
#pragma unroll
        for (int j = 0; j < 4; ++j)
            b[j] = *(const bf8*)&stage[cur][1][(pw + 16 * j + lr) * 32 + quad * 8];
#pragma unroll
        for (int i = 0; i < 4; ++i)
#pragma unroll
            for (int j = 0; j < 4; ++j)
                acc[i][j] = __builtin_amdgcn_mfma_f32_16x16x32_bf16(a[i], b[j], acc[i][j], 0, 0, 0);
        __syncthreads();
    }
#undef STAGE_P
    float* op = part + (size_t)z * 1048576;
#pragma unroll
    for (int i = 0; i < 4; ++i) {
        int mrow = mbase + mw + 16 * i + quad * 4;
#pragma unroll
        for (int j = 0; j < 4; ++j) {
            int pcol = pbase + pw + 16 * j + lr;
#pragma unroll
            for (int r = 0; r < 4; ++r)
                op[(size_t)(mrow + r) * HW + pcol] = acc[i][j][r];
        }
    }
}

// aligned[c2][p]: 8 z-slices summed inline; mask_a/norm_a recomputed from
// fa_parse; bg evaluated algebraically from bgbuf (base - rowsum)
__global__ void k_combine8(const float* __restrict__ part, const float* __restrict__ bgbuf,
                           const int* __restrict__ fa_parse, float* __restrict__ aligned) {
    int p = blockIdx.x * 256 + threadIdx.x;
    int c2 = blockIdx.y;
    int jj = p >> 6, ii = p & 63;
    int off = (4 * jj) * 256 + 4 * ii;
    float tot_c = bgbuf[256 + c2];
    float num = 0.f, s = 0.f;
    for (int k = 0; k < 3; ++k) {
        float ma = (fa_parse[(k + 1) * 65536 + off] != 0) ? 1.f : 0.f;
        s += ma;
        float den = E50f * (4096.0f - bgbuf[k * 65 + 64]);
        float nu  = E50f * (tot_c - bgbuf[k * 65 + c2]);
        size_t rd = (size_t)(k * 65 + 64) * HW + p;
        size_t rn = (size_t)(k * 65 + c2) * HW + p;
#pragma unroll
        for (int z = 0; z < 8; ++z) {
            den += part[(size_t)z * 1048576 + rd];
            nu  += part[(size_t)z * 1048576 + rn];
        }
        num += ma * (nu / den);
    }
    aligned[c2 * HW + p] = num / fmaxf(s, 1.f);
}

// bilinear align_corners 64->256, 4 outputs per thread (float4 stores)
__global__ void k_bilin_up(const float* __restrict__ aligned, float* __restrict__ out) {
    int idx = (blockIdx.x * 256 + threadIdx.x) * 4;   // 0..65532
    int c2 = blockIdx.y;
    int y = idx >> 8;
    float ry = y * (63.0f / 255.0f);
    int y0 = (int)ry; y0 = min(y0, 63); int y1 = min(y0 + 1, 63);
    float wy = ry - (float)y0;
    const float* a = aligned + c2 * HW;
    float4 o;
    float* op = &o.x;
#pragma unroll
    for (int u = 0; u < 4; ++u) {
        int x = (idx & 255) + u;
        float rx = x * (63.0f / 255.0f);
        int x0 = (int)rx; x0 = min(x0, 63); int x1 = min(x0 + 1, 63);
        float wx = rx - (float)x0;
        float r0 = a[y0 * 64 + x0] * (1.f - wx) + a[y0 * 64 + x1] * wx;
        float r1 = a[y1 * 64 + x0] * (1.f - wx) + a[y1 * 64 + x1] * wx;
        op[u] = r0 * (1.f - wy) + r1 * wy;
    }
    *(float4*)&out[c2 * 65536 + idx] = o;
}

extern "C" void kernel_launch(void* const* d_in, const int* in_sizes, int n_in,
                              void* d_out, int out_size, void* d_ws, size_t ws_size,
                              hipStream_t stream) {
    const float* unalign_fb = (const float*)d_in[0];   // (1,64,256,256)
    const float* fa         = (const float*)d_in[1];   // (1,256,64,64)
    const int*   fa_parse   = (const int*)d_in[2];     // (1,4,256,256)
    const float* fb         = (const float*)d_in[3];   // (1,256,64,64)
    const int*   fb_parse   = (const int*)d_in[4];     // (1,4,256,256)
    float* out = (float*)d_out;                         // (1,64,256,256)

    float* w = (float*)d_ws;
    float* mu       = w;                   // 512
    float* ssq_part = w + 512;             // 65536
    float* bgbuf    = w + 66048;           // 320 (rowsum[256] + tot[64])
    float* part     = w + 66368;           // 8*1048576
    float* aligned  = w + 8454976;         // 262144
    USH* faT  = (USH*)(w + 8717120);       // [kc=8][4096p][32] fp16
    USH* fbT  = (USH*)(w + 9241408);       // [kc=8][4096q][32] fp16
    USH* vtT  = (USH*)(w + 9765696);       // [qc=128][256m][32] bf16
    USH* Ebuf = (USH*)(w + 10289984);      // [qc=128][4096p][32] bf16
    // total ~18.7M floats = ~74.7 MB

    k_channel_mean<<<dim3(512), dim3(256), 0, stream>>>(fa, fb, mu);
    k_norm_ss<<<dim3(16, 8, 2), dim3(256), 0, stream>>>(fa, fb, mu, ssq_part);
    k_norm_split_t<<<dim3(64, 4, 2), dim3(256), 0, stream>>>(fa, fb, mu, ssq_part, faT, fbT);
    hipMemsetAsync(bgbuf, 0, 320 * sizeof(float), stream);
    k_bilin_down_vt<<<dim3(16, 64), dim3(256), 0, stream>>>(unalign_fb, fb_parse, vtT, bgbuf);

    k_gemm_s_exp<<<dim3(32, 32), dim3(256), 0, stream>>>(faT, fbT, Ebuf);
    k_pv<<<dim3(32, 2, 8), dim3(256), 0, stream>>>(vtT, Ebuf, part);

    k_combine8<<<dim3(16, 64), dim3(256), 0, stream>>>(part, bgbuf, fa_parse, aligned);
    k_bilin_up<<<dim3(64, 64), dim3(256), 0, stream>>>(aligned, out);
}

// Round 6
// 136.270 us; speedup vs baseline: 3.6144x; 1.1056x over previous
//
#include <hip/hip_runtime.h>
#include <math.h>

#define HW 4096      // 64*64 feature locations
#define CC 256       // feature channels
#define C2 64        // value channels
#define E50f 1.928749848e-22f   // expf(-50)

typedef unsigned short USH;
typedef __attribute__((ext_vector_type(8))) _Float16 f16x8;
typedef __attribute__((ext_vector_type(8))) short bf8;
typedef __attribute__((ext_vector_type(4))) float f32x4;

__device__ __forceinline__ USH f2bf(float x) {
    unsigned u = __float_as_uint(x);
    u += 0x7fff + ((u >> 16) & 1);   // round-to-nearest-even
    return (USH)(u >> 16);
}
__device__ __forceinline__ USH f2h(float x) {
    _Float16 h = (_Float16)x;        // v_cvt_f16_f32, RTNE
    return *(USH*)&h;
}

// async global->LDS DMA, 16B per lane; LDS base must be wave-uniform
__device__ __forceinline__ void gl2lds16(const USH* g, USH* l) {
    __builtin_amdgcn_global_load_lds(
        (const __attribute__((address_space(1))) void*)g,
        (__attribute__((address_space(3))) void*)l, 16, 0, 0);
}

// ---------------------------------------------------------------------------
// D1: merged prep. blocks [0,512): per-channel means of fa/fb.
//     blocks [512,1536): bilinear 256->64 of unalign_fb fused with mask_b,
//     vtT build (chunked [qc][256m][32] bf16) and per-(pblock) bg partials.
// bgp layout: [pblk][320]: [0..255] rowsum[m] partials, [256..319] tot[c2].
__global__ void k_prep1(const float* __restrict__ fa, const float* __restrict__ fb,
                        float* __restrict__ mu,
                        const float* __restrict__ ufb_src, const int* __restrict__ fb_parse,
                        USH* __restrict__ vtT, float* __restrict__ bgp) {
    __shared__ float4 sred[256];
    int t = threadIdx.x;
    if (blockIdx.x < 512) {
        int b = blockIdx.x;
        const float* src = (b < CC) ? (fa + b * HW) : (fb + (b - CC) * HW);
        float s = 0.f;
        for (int q = t; q < HW; q += 256) s += src[q];
        sred[t].x = s;
        __syncthreads();
        for (int st = 128; st > 0; st >>= 1) {
            if (t < st) sred[t].x += sred[t + st].x;
            __syncthreads();
        }
        if (t == 0) mu[b] = sred[0].x * (1.0f / HW);
        return;
    }
    int bid = blockIdx.x - 512;
    int pblk = bid & 15, c = bid >> 4;
    int p = pblk * 256 + t;
    int j = p >> 6, i = p & 63;
    int off = (4 * j) * 256 + 4 * i;   // nearest: src = 4*dst
    float m0 = (fb_parse[1 * 65536 + off] != 0) ? 1.f : 0.f;
    float m1 = (fb_parse[2 * 65536 + off] != 0) ? 1.f : 0.f;
    float m2 = (fb_parse[3 * 65536 + off] != 0) ? 1.f : 0.f;
    float ry = j * (255.0f / 63.0f);
    int y0 = (int)ry; y0 = min(y0, 255); int y1 = min(y0 + 1, 255);
    float wy = ry - (float)y0;
    float rx = i * (255.0f / 63.0f);
    int x0 = (int)rx; x0 = min(x0, 255); int x1 = min(x0 + 1, 255);
    float wx = rx - (float)x0;
    const float* sc = ufb_src + c * 65536;
    float r0 = sc[y0 * 256 + x0] * (1.f - wx) + sc[y0 * 256 + x1] * wx;
    float r1 = sc[y1 * 256 + x0] * (1.f - wx) + sc[y1 * 256 + x1] * wx;
    float v = r0 * (1.f - wy) + r1 * wy;
    size_t cbase = (size_t)(p >> 5) * 8192 + (p & 31);
    vtT[cbase + (0 * 65 + c) * 32] = f2bf(v * m0);
    vtT[cbase + (1 * 65 + c) * 32] = f2bf(v * m1);
    vtT[cbase + (2 * 65 + c) * 32] = f2bf(v * m2);
    if (c == 0) {
        vtT[cbase + 64 * 32]  = f2bf(m0);
        vtT[cbase + 129 * 32] = f2bf(m1);
        vtT[cbase + 194 * 32] = f2bf(m2);
        for (int m = 195; m < 256; ++m) vtT[cbase + m * 32] = 0;
    }
    sred[t] = make_float4(v, v * m0, v * m1, v * m2);
    __syncthreads();
    for (int st = 128; st > 0; st >>= 1) {
        if (t < st) {
            float4 o = sred[t + st];
            sred[t].x += o.x; sred[t].y += o.y; sred[t].z += o.z; sred[t].w += o.w;
        }
        __syncthreads();
    }
    if (t == 0) {
        float4 r = sred[0];
        bgp[pblk * 320 + 256 + c]     = r.x;   // tot[c]
        bgp[pblk * 320 + 0 * 65 + c]  = r.y;   // rowsum value rows
        bgp[pblk * 320 + 1 * 65 + c]  = r.z;
        bgp[pblk * 320 + 2 * 65 + c]  = r.w;
    }
    __syncthreads();
    if (c == 0) {   // mask-row sums (block-uniform branch)
        sred[t] = make_float4(m0, m1, m2, 0.f);
        __syncthreads();
        for (int st = 128; st > 0; st >>= 1) {
            if (t < st) {
                float4 o = sred[t + st];
                sred[t].x += o.x; sred[t].y += o.y; sred[t].z += o.z;
            }
            __syncthreads();
        }
        if (t == 0) {
            float4 r = sred[0];
            bgp[pblk * 320 + 64]  = r.x;
            bgp[pblk * 320 + 129] = r.y;
            bgp[pblk * 320 + 194] = r.z;
        }
    }
}

// D2: partial sum of squares over 32-channel chunks -> ssq_part[which][8][4096]
__global__ void k_norm_ss(const float* __restrict__ fa, const float* __restrict__ fb,
                          const float* __restrict__ mu, float* __restrict__ ssq_part) {
    int which = blockIdx.z;
    const float* src = which ? fb : fa;
    int p = blockIdx.x * 256 + threadIdx.x;
    int c0 = blockIdx.y * 32;
    float ss = 0.f;
    for (int c = c0; c < c0 + 32; ++c) {
        float v = src[c * HW + p] - mu[which * CC + c];
        ss += v * v;
    }
    ssq_part[(which * 8 + blockIdx.y) * HW + p] = ss;
}

// D3: center + L2-normalize + fp16 cast + transpose into chunked layout [kc][p][32]
__global__ __launch_bounds__(256) void k_norm_split_t(
    const float* __restrict__ fa, const float* __restrict__ fb,
    const float* __restrict__ mu, const float* __restrict__ ssq_part,
    USH* __restrict__ faT, USH* __restrict__ fbT) {
    __shared__ float tile[64][68];
    int which = blockIdx.z;
    const float* src = which ? fb : fa;
    USH* dst = which ? fbT : faT;
    int p0 = blockIdx.x * 64;
    int c0 = blockIdx.y * 64;
    int t = threadIdx.x;
    {
        int c_r = t >> 2, seg = t & 3;
        const float* s = &src[(size_t)(c0 + c_r) * HW + p0 + seg * 16];
#pragma unroll
        for (int k = 0; k < 4; ++k)
            *(float4*)&tile[c_r][seg * 16 + k * 4] = *(const float4*)&s[k * 4];
    }
    __syncthreads();
    {
        int p_r = t >> 2, seg = t & 3;
        int cl = seg * 16;
        float ss = 0.f;
#pragma unroll
        for (int z = 0; z < 8; ++z) ss += ssq_part[(which * 8 + z) * HW + p0 + p_r];
        float rinv = rsqrtf(ss);
        union { USH us[8]; uint4 v; } h0, h1;
#pragma unroll
        for (int j = 0; j < 8; ++j)
            h0.us[j] = f2h((tile[cl + j][p_r] - mu[which * CC + c0 + cl + j]) * rinv);
#pragma unroll
        for (int j = 0; j < 8; ++j)
            h1.us[j] = f2h((tile[cl + 8 + j][p_r] - mu[which * CC + c0 + cl + 8 + j]) * rinv);
        int kc = (c0 >> 5) + (seg >> 1);
        size_t base = (size_t)kc * 131072 + (size_t)(p0 + p_r) * 32 + (seg & 1) * 16;
        *(uint4*)&dst[base] = h0.v;
        *(uint4*)&dst[base + 8] = h1.v;
    }
}

// D4: fused attention: S = fa·fb (fp16 MFMA), E = exp(100S-50) bf16 in LDS,
//     PV = vtT·E^T (bf16 MFMA) accumulated in registers across the z-chunk.
// Block: p-tile 64 (blockIdx.x), z-chunk 512 q (blockIdx.y). 4 q-tiles of 128.
__global__ __launch_bounds__(256, 2) void k_attn(
    const USH* __restrict__ faT, const USH* __restrict__ fbT,
    const USH* __restrict__ vtT, float* __restrict__ part) {
    __shared__ USH sA[2][2048];     // faT stage [64p][32k] fp16
    __shared__ USH sB[2][4096];     // fbT stage [128q][32k] fp16
    __shared__ USH sV[2][8192];     // vtT stage [256m][32q] bf16
    __shared__ USH sE[64 * 136];    // E tile [64p][128q + pad] bf16
    int t = threadIdx.x;
    int p0 = blockIdx.x * 64;
    int z = blockIdx.y;
    int w = t >> 6, lane = t & 63, lr = lane & 15, quad = lane >> 4;
    f32x4 accp[4][4] = {};          // PV acc: m=64w+16i+quad*4+r, p=p0+16j+lr

    const USH* gA = faT + (size_t)p0 * 32;

#define DMA_AB(buf, kc, q0)                                                          \
    do {                                                                             \
        gl2lds16(gA + (size_t)(kc) * 131072 + w * 512 + lane * 8, &sA[buf][w * 512]);\
        _Pragma("unroll")                                                            \
        for (int cc = 0; cc < 2; ++cc)                                               \
            gl2lds16(fbT + (size_t)(kc) * 131072 + (size_t)(q0) * 32 +               \
                         (2 * w + cc) * 512 + lane * 8,                              \
                     &sB[buf][(2 * w + cc) * 512]);                                  \
    } while (0)
#define DMA_V(buf, qc)                                                               \
    do {                                                                             \
        _Pragma("unroll")                                                            \
        for (int cc = 0; cc < 4; ++cc)                                               \
            gl2lds16(vtT + (size_t)(qc) * 8192 + (4 * w + cc) * 512 + lane * 8,      \
                     &sV[buf][(4 * w + cc) * 512]);                                  \
    } while (0)

    DMA_AB(0, 0, z * 512);
    __syncthreads();
    for (int qt = 0; qt < 4; ++qt) {
        int q0 = z * 512 + qt * 128;
        f32x4 accs[2][4] = {};      // S acc: q=32w+16i+quad*4+r, p=16j+lr
        for (int kc = 0; kc < 8; ++kc) {
            int cur = kc & 1;
            if (kc < 7) DMA_AB(cur ^ 1, kc + 1, q0);
            else        DMA_V(0, z * 16 + qt * 4);
            f16x8 a[2], b[4];
#pragma unroll
            for (int i = 0; i < 2; ++i)
                a[i] = *(const f16x8*)&sB[cur][(32 * w + 16 * i + lr) * 32 + quad * 8];
#pragma unroll
            for (int jj = 0; jj < 4; ++jj)
                b[jj] = *(const f16x8*)&sA[cur][(16 * jj + lr) * 32 + quad * 8];
#pragma unroll
            for (int i = 0; i < 2; ++i)
#pragma unroll
                for (int jj = 0; jj < 4; ++jj)
                    accs[i][jj] = __builtin_amdgcn_mfma_f32_16x16x32_f16(a[i], b[jj], accs[i][jj], 0, 0, 0);
            __syncthreads();
        }
        // exp -> bf16 -> transposed E tile in LDS: E[p][q]
#pragma unroll
        for (int i = 0; i < 2; ++i)
#pragma unroll
            for (int jj = 0; jj < 4; ++jj) {
                unsigned u0 = ((unsigned)f2bf(__expf(fmaf(100.f, accs[i][jj][1], -50.f))) << 16)
                            | (unsigned)f2bf(__expf(fmaf(100.f, accs[i][jj][0], -50.f)));
                unsigned u1 = ((unsigned)f2bf(__expf(fmaf(100.f, accs[i][jj][3], -50.f))) << 16)
                            | (unsigned)f2bf(__expf(fmaf(100.f, accs[i][jj][2], -50.f)));
                int addr = (16 * jj + lr) * 136 + 32 * w + 16 * i + 4 * quad;
                uint2 u; u.x = u0; u.y = u1;
                *(uint2*)&sE[addr] = u;
            }
        __syncthreads();
        for (int kc = 0; kc < 4; ++kc) {
            int cur = kc & 1;
            if (kc < 3)      DMA_V(cur ^ 1, z * 16 + qt * 4 + kc + 1);
            else if (qt < 3) DMA_AB(0, 0, q0 + 128);
            bf8 av[4], be[4];
#pragma unroll
            for (int i = 0; i < 4; ++i)
                av[i] = *(const bf8*)&sV[cur][(64 * w + 16 * i + lr) * 32 + quad * 8];
#pragma unroll
            for (int jj = 0; jj < 4; ++jj)
                be[jj] = *(const bf8*)&sE[(16 * jj + lr) * 136 + kc * 32 + quad * 8];
#pragma unroll
            for (int i = 0; i < 4; ++i)
#pragma unroll
                for (int jj = 0; jj < 4; ++jj)
                    accp[i][jj] = __builtin_amdgcn_mfma_f32_16x16x32_bf16(av[i], be[jj], accp[i][jj], 0, 0, 0);
            __syncthreads();
        }
    }
#undef DMA_AB
#undef DMA_V
    float* op = part + (size_t)z * 1048576;
#pragma unroll
    for (int i = 0; i < 4; ++i) {
        int m = 64 * w + 16 * i + quad * 4;
#pragma unroll
        for (int jj = 0; jj < 4; ++jj) {
            int pc = p0 + 16 * jj + lr;
#pragma unroll
            for (int r = 0; r < 4; ++r)
                op[(size_t)(m + r) * HW + pc] = accp[i][jj][r];
        }
    }
}

// D5: aligned[c2][p]: 8 z-slices summed inline; mask_a/norm_a from fa_parse;
//     bg terms from the 16 per-pblock partial slots
__global__ void k_combine8(const float* __restrict__ part, const float* __restrict__ bgp,
                           const int* __restrict__ fa_parse, float* __restrict__ aligned) {
    __shared__ float sums[8];
    int t = threadIdx.x;
    int c2 = blockIdx.y;
    if (t < 7) {
        int idx = (t < 3) ? (t * 65 + 64) : ((t < 6) ? (t - 3) * 65 + c2 : 256 + c2);
        float s = 0.f;
#pragma unroll
        for (int pb = 0; pb < 16; ++pb) s += bgp[pb * 320 + idx];
        sums[t] = s;
    }
    __syncthreads();
    int p = blockIdx.x * 256 + t;
    int jj = p >> 6, ii = p & 63;
    int off = (4 * jj) * 256 + 4 * ii;
    float num = 0.f, s = 0.f;
    for (int k = 0; k < 3; ++k) {
        float ma = (fa_parse[(k + 1) * 65536 + off] != 0) ? 1.f : 0.f;
        s += ma;
        float den = E50f * (4096.0f - sums[k]);
        float nu  = E50f * (sums[6] - sums[3 + k]);
        size_t rd = (size_t)(k * 65 + 64) * HW + p;
        size_t rn = (size_t)(k * 65 + c2) * HW + p;
#pragma unroll
        for (int z = 0; z < 8; ++z) {
            den += part[(size_t)z * 1048576 + rd];
            nu  += part[(size_t)z * 1048576 + rn];
        }
        num += ma * (nu / den);
    }
    aligned[c2 * HW + p] = num / fmaxf(s, 1.f);
}

// D6: bilinear align_corners 64->256, 4 outputs per thread
__global__ void k_bilin_up(const float* __restrict__ aligned, float* __restrict__ out) {
    int idx = (blockIdx.x * 256 + threadIdx.x) * 4;
    int c2 = blockIdx.y;
    int y = idx >> 8;
    float ry = y * (63.0f / 255.0f);
    int y0 = (int)ry; y0 = min(y0, 63); int y1 = min(y0 + 1, 63);
    float wy = ry - (float)y0;
    const float* a = aligned + c2 * HW;
    float4 o;
    float* op = &o.x;
#pragma unroll
    for (int u = 0; u < 4; ++u) {
        int x = (idx & 255) + u;
        float rx = x * (63.0f / 255.0f);
        int x0 = (int)rx; x0 = min(x0, 63); int x1 = min(x0 + 1, 63);
        float wx = rx - (float)x0;
        float r0 = a[y0 * 64 + x0] * (1.f - wx) + a[y0 * 64 + x1] * wx;
        float r1 = a[y1 * 64 + x0] * (1.f - wx) + a[y1 * 64 + x1] * wx;
        op[u] = r0 * (1.f - wy) + r1 * wy;
    }
    *(float4*)&out[c2 * 65536 + idx] = o;
}

extern "C" void kernel_launch(void* const* d_in, const int* in_sizes, int n_in,
                              void* d_out, int out_size, void* d_ws, size_t ws_size,
                              hipStream_t stream) {
    const float* unalign_fb = (const float*)d_in[0];   // (1,64,256,256)
    const float* fa         = (const float*)d_in[1];   // (1,256,64,64)
    const int*   fa_parse   = (const int*)d_in[2];     // (1,4,256,256)
    const float* fb         = (const float*)d_in[3];   // (1,256,64,64)
    const int*   fb_parse   = (const int*)d_in[4];     // (1,4,256,256)
    float* out = (float*)d_out;                         // (1,64,256,256)

    float* w = (float*)d_ws;
    float* mu       = w;                   // 512
    float* ssq_part = w + 512;             // 65536
    float* bgp      = w + 66048;           // 16*320 = 5120
    float* part     = w + 71168;           // 8*1048576
    float* aligned  = w + 8459776;         // 262144
    USH* faT = (USH*)(w + 8721920);        // [kc=8][4096p][32] fp16
    USH* fbT = (USH*)(w + 9246208);        // [kc=8][4096q][32] fp16
    USH* vtT = (USH*)(w + 9770496);        // [qc=128][256m][32] bf16
    // total ~10.3M floats = ~41.2 MB

    k_prep1<<<dim3(1536), dim3(256), 0, stream>>>(fa, fb, mu, unalign_fb, fb_parse, vtT, bgp);
    k_norm_ss<<<dim3(16, 8, 2), dim3(256), 0, stream>>>(fa, fb, mu, ssq_part);
    k_norm_split_t<<<dim3(64, 4, 2), dim3(256), 0, stream>>>(fa, fb, mu, ssq_part, faT, fbT);
    k_attn<<<dim3(64, 8), dim3(256), 0, stream>>>(faT, fbT, vtT, part);
    k_combine8<<<dim3(16, 64), dim3(256), 0, stream>>>(part, bgp, fa_parse, aligned);
    k_bilin_up<<<dim3(64, 64), dim3(256), 0, stream>>>(aligned, out);
}